// Round 1
// baseline (1635.474 us; speedup 1.0000x reference)
//
#include <hip/hip_runtime.h>
#include <cmath>

#define T 2048
#define H 1024
#define NH 16
#define NKV 4
#define DH 64
#define NE 8
#define FF 1024
#define QKVN ((NH + 2 * NKV) * DH) /* 1536 */
#define EPS 1e-5f
#define ROPE_THETA 500000.0f
#define ATTN_SCALE 0.125f /* D^-0.5 */

// ---------------- rmsnorm (rows of 1024) ----------------
__global__ __launch_bounds__(256) void rmsnorm1024(const float* __restrict__ x,
                                                   const float* __restrict__ w,
                                                   float* __restrict__ y) {
  int row = blockIdx.x;
  const float4* x4 = (const float4*)(x + (size_t)row * H);
  float4 v = x4[threadIdx.x];
  float s = v.x * v.x + v.y * v.y + v.z * v.z + v.w * v.w;
  #pragma unroll
  for (int o = 32; o; o >>= 1) s += __shfl_down(s, o, 64);
  __shared__ float red[4];
  if ((threadIdx.x & 63) == 0) red[threadIdx.x >> 6] = s;
  __syncthreads();
  s = red[0] + red[1] + red[2] + red[3];
  float inv = rsqrtf(s * (1.0f / (float)H) + EPS);
  float4 wv = ((const float4*)w)[threadIdx.x];
  float4 o4;
  o4.x = v.x * inv * wv.x;
  o4.y = v.y * inv * wv.y;
  o4.z = v.z * inv * wv.z;
  o4.w = v.w * inv * wv.w;
  ((float4*)(y + (size_t)row * H))[threadIdx.x] = o4;
}

// ---------------- generic fp32 GEMM, 64x64x16 tile, optional grouped rows ----
#define BM 64
#define BN 64
#define BK 16
#define APAD 4

__global__ __launch_bounds__(256) void gemm64(const float* __restrict__ A,
                                              const float* __restrict__ B,
                                              float* __restrict__ C, int M, int N,
                                              int K, const int* __restrict__ row_offs,
                                              long long strideB) {
  int e = blockIdx.z;
  int rbeg = 0, rend = M;
  if (row_offs) { rbeg = row_offs[e]; rend = row_offs[e + 1]; }
  long long m0 = rbeg + (long long)blockIdx.y * BM;
  if (m0 >= rend) return;
  long long n0 = (long long)blockIdx.x * BN;
  const float* Bp = B + (long long)e * strideB;

  __shared__ float As[BK][BM + APAD];
  __shared__ float Bs[BK][BN];

  int tid = threadIdx.x;
  int tx = tid & 15, ty = tid >> 4;
  int a_m = tid >> 2;
  int a_k = (tid & 3) << 2;
  int b_k = tid >> 4;
  int b_n = (tid & 15) << 2;

  float acc[4][4] = {};

  for (int k0 = 0; k0 < K; k0 += BK) {
    float4 av = make_float4(0.f, 0.f, 0.f, 0.f);
    long long gm = m0 + a_m;
    if (gm < rend) av = *(const float4*)(A + gm * K + k0 + a_k);
    As[a_k + 0][a_m] = av.x;
    As[a_k + 1][a_m] = av.y;
    As[a_k + 2][a_m] = av.z;
    As[a_k + 3][a_m] = av.w;
    *(float4*)&Bs[b_k][b_n] = *(const float4*)(Bp + (long long)(k0 + b_k) * N + n0 + b_n);
    __syncthreads();
    #pragma unroll
    for (int kk = 0; kk < BK; kk++) {
      float4 ra = *(const float4*)&As[kk][ty << 2];
      float4 rb = *(const float4*)&Bs[kk][tx << 2];
      float a_[4] = {ra.x, ra.y, ra.z, ra.w};
      float b_[4] = {rb.x, rb.y, rb.z, rb.w};
      #pragma unroll
      for (int i = 0; i < 4; i++)
        #pragma unroll
        for (int j = 0; j < 4; j++) acc[i][j] += a_[i] * b_[j];
    }
    __syncthreads();
  }
  #pragma unroll
  for (int i = 0; i < 4; i++) {
    long long gm = m0 + (ty << 2) + i;
    if (gm < rend) {
      float4 o4 = make_float4(acc[i][0], acc[i][1], acc[i][2], acc[i][3]);
      *(float4*)(C + gm * N + n0 + (tx << 2)) = o4;
    }
  }
}

// ---------------- RoPE + per-head rmsnorm on q,k (in place) ----------------
__global__ __launch_bounds__(64) void rope_norm_kernel(float* __restrict__ qkv,
                                                       const int* __restrict__ positions) {
  int b = blockIdx.x;
  int t = b / (NH + NKV);
  int hh = b % (NH + NKV);
  float* ptr = qkv + (long long)t * QKVN + ((hh < NH) ? hh * DH : NH * DH + (hh - NH) * DH);
  int d = threadIdx.x;
  float v = ptr[d];
  int fi = d & 31;
  float inv_freq = __powf(ROPE_THETA, -(float)fi / 32.0f);
  float ang = (float)positions[t] * inv_freq;
  float c = cosf(ang), s = sinf(ang);
  float other = __shfl_xor(v, 32, 64);
  float r = (d < 32) ? (v * c - other * s) : (v * c + other * s);
  float sq = r * r;
  #pragma unroll
  for (int off = 32; off; off >>= 1) sq += __shfl_xor(sq, off, 64);
  ptr[d] = r * rsqrtf(sq * (1.0f / (float)DH) + EPS);
}

// ---------------- causal flash attention (fp32) ----------------
// grid (T/64, NH), block 256. lane = q-row within tile, wave g handles keys j in [g*8, g*8+8) per 32-tile.
__global__ __launch_bounds__(256) void attn_kernel(const float* __restrict__ qkv,
                                                   float* __restrict__ ao) {
  int h = blockIdx.y;
  int tile0 = blockIdx.x * 64;
  int lane = threadIdx.x & 63;
  int g = threadIdx.x >> 6;
  int t = tile0 + lane;
  int kvh = h >> 2;

  const float* qrow = qkv + (long long)t * QKVN + h * DH;
  float q[DH], O[DH];
  #pragma unroll
  for (int d = 0; d < DH; d++) {
    q[d] = qrow[d] * ATTN_SCALE;
    O[d] = 0.f;
  }
  float m = -1e30f, l = 0.f;

  __shared__ float Ks[32][DH];
  __shared__ float Vs[32][DH];

  int kmax = tile0 + 64;
  for (int kb = 0; kb < kmax; kb += 32) {
    int tid = threadIdx.x;
    #pragma unroll
    for (int it = 0; it < 2; it++) {
      int idx4 = tid + it * 256;
      int j = idx4 >> 4;
      int dd = (idx4 & 15) << 2;
      long long rowb = (long long)(kb + j) * QKVN + kvh * DH + dd;
      *(float4*)&Ks[j][dd] = *(const float4*)(qkv + rowb + NH * DH);
      *(float4*)&Vs[j][dd] = *(const float4*)(qkv + rowb + (NH + NKV) * DH);
    }
    __syncthreads();
    #pragma unroll 4
    for (int j2 = 0; j2 < 8; j2++) {
      int j = g * 8 + j2;
      int tk = kb + j;
      float s = 0.f;
      #pragma unroll
      for (int d = 0; d < DH; d++) s += q[d] * Ks[j][d];
      bool valid = (tk <= t);
      float sv = valid ? s : -1e30f;
      float mn = fmaxf(m, sv);
      float alpha = __expf(m - mn);
      float p = valid ? __expf(sv - mn) : 0.f;
      l = l * alpha + p;
      #pragma unroll
      for (int d = 0; d < DH; d++) O[d] = O[d] * alpha + p * Vs[j][d];
      m = mn;
    }
    __syncthreads();
  }

  // combine the 4 per-wave partials
  __shared__ float mred[4][64], lred[4][64];
  mred[g][lane] = m;
  lred[g][lane] = l;
  __syncthreads();
  float mstar = fmaxf(fmaxf(mred[0][lane], mred[1][lane]), fmaxf(mred[2][lane], mred[3][lane]));
  float lstar = 0.f;
  #pragma unroll
  for (int gg = 0; gg < 4; gg++) lstar += lred[gg][lane] * __expf(mred[gg][lane] - mstar);
  float f = __expf(m - mstar);
  __shared__ float Obuf[64][DH + 1];
  for (int gg = 0; gg < 4; gg++) {
    if (g == gg) {
      if (gg == 0) {
        #pragma unroll
        for (int d = 0; d < DH; d++) Obuf[lane][d] = f * O[d];
      } else {
        #pragma unroll
        for (int d = 0; d < DH; d++) Obuf[lane][d] += f * O[d];
      }
    }
    __syncthreads();
  }
  float invl = 1.0f / lstar;
  #pragma unroll
  for (int i = 0; i < 16; i++) {
    int d = g * 16 + i;
    ao[(long long)t * (NH * DH) + h * DH + d] = Obuf[lane][d] * invl;
  }
}

// ---------------- elementwise helpers ----------------
__global__ void add_kernel(const float* __restrict__ a, const float* __restrict__ b,
                           float* __restrict__ y, int n4) {
  int i = blockIdx.x * blockDim.x + threadIdx.x;
  if (i >= n4) return;
  float4 av = ((const float4*)a)[i];
  float4 bv = ((const float4*)b)[i];
  av.x += bv.x; av.y += bv.y; av.z += bv.z; av.w += bv.w;
  ((float4*)y)[i] = av;
}

__global__ void silumul_kernel(float* __restrict__ g1, const float* __restrict__ g2, int n4) {
  int i = blockIdx.x * blockDim.x + threadIdx.x;
  if (i >= n4) return;
  float4 a = ((float4*)g1)[i];
  float4 b = ((const float4*)g2)[i];
  a.x = a.x / (1.f + __expf(-a.x)) * b.x;
  a.y = a.y / (1.f + __expf(-a.y)) * b.y;
  a.z = a.z / (1.f + __expf(-a.z)) * b.z;
  a.w = a.w / (1.f + __expf(-a.w)) * b.w;
  ((float4*)g1)[i] = a;
}

// ---------------- router (top-1 + sigmoid gate) ----------------
__global__ __launch_bounds__(64) void router_kernel(const float* __restrict__ h2,
                                                    const float* __restrict__ rw,
                                                    int* __restrict__ idx,
                                                    float* __restrict__ gate,
                                                    int* __restrict__ counts) {
  int t = blockIdx.x;
  int lane = threadIdx.x;
  float acc[NE] = {};
  for (int k = lane; k < H; k += 64) {
    float hv = h2[(long long)t * H + k];
    float4 r0 = *(const float4*)(rw + (long long)k * NE);
    float4 r1 = *(const float4*)(rw + (long long)k * NE + 4);
    acc[0] += hv * r0.x; acc[1] += hv * r0.y; acc[2] += hv * r0.z; acc[3] += hv * r0.w;
    acc[4] += hv * r1.x; acc[5] += hv * r1.y; acc[6] += hv * r1.z; acc[7] += hv * r1.w;
  }
  #pragma unroll
  for (int off = 32; off; off >>= 1)
    #pragma unroll
    for (int e2 = 0; e2 < NE; e2++) acc[e2] += __shfl_down(acc[e2], off, 64);
  if (lane == 0) {
    int best = 0;
    float bv = acc[0];
    #pragma unroll
    for (int e2 = 1; e2 < NE; e2++)
      if (acc[e2] > bv) { bv = acc[e2]; best = e2; }
    idx[t] = best;
    gate[t] = 1.f / (1.f + expf(-bv));
    atomicAdd(&counts[best], 1);
  }
}

__global__ void zero_counts_kernel(int* c) {
  if (threadIdx.x < 2 * NE) c[threadIdx.x] = 0;
}

__global__ void scan_kernel(const int* __restrict__ counts, int* __restrict__ offs) {
  if (threadIdx.x == 0) {
    int s = 0;
    for (int e2 = 0; e2 < NE; e2++) { offs[e2] = s; s += counts[e2]; }
    offs[NE] = s;
  }
}

__global__ void assign_kernel(const int* __restrict__ idx, const int* __restrict__ offs,
                              int* __restrict__ cnt2, int* __restrict__ perm,
                              int* __restrict__ pos) {
  int t = blockIdx.x * blockDim.x + threadIdx.x;
  if (t >= T) return;
  int e2 = idx[t];
  int p = offs[e2] + atomicAdd(&cnt2[e2], 1);
  pos[t] = p;
  perm[p] = t;
}

__global__ __launch_bounds__(256) void gather_kernel(const float* __restrict__ h2,
                                                     const float* __restrict__ gate,
                                                     const int* __restrict__ perm,
                                                     float* __restrict__ xg) {
  int p = blockIdx.x;
  int t = perm[p];
  float g = gate[t];
  float4 v = ((const float4*)(h2 + (long long)t * H))[threadIdx.x];
  v.x *= g; v.y *= g; v.z *= g; v.w *= g;
  ((float4*)(xg + (long long)p * H))[threadIdx.x] = v;
}

__global__ __launch_bounds__(256) void final_add_kernel(float* __restrict__ out,
                                                        const float* __restrict__ outp,
                                                        const int* __restrict__ pos) {
  int t = blockIdx.x;
  int p = pos[t];
  const float4* src = (const float4*)(outp + (long long)p * H);
  float4* dst = (float4*)(out + (long long)t * H);
  float4 a = dst[threadIdx.x];
  float4 b = src[threadIdx.x];
  a.x += b.x; a.y += b.y; a.z += b.z; a.w += b.w;
  dst[threadIdx.x] = a;
}

// ---------------- launcher ----------------
extern "C" void kernel_launch(void* const* d_in, const int* in_sizes, int n_in,
                              void* d_out, int out_size, void* d_ws, size_t ws_size,
                              hipStream_t stream) {
  const int* positions = (const int*)d_in[0];
  const float* hidden = (const float*)d_in[1];
  const float* ln1_w = (const float*)d_in[2];
  const float* ln2_w = (const float*)d_in[3];
  const float* wqkv = (const float*)d_in[4];
  const float* wo = (const float*)d_in[5];
  const float* router_w = (const float*)d_in[6];
  const float* w_gate = (const float*)d_in[7];
  const float* w_up = (const float*)d_in[8];
  const float* w_down = (const float*)d_in[9];
  const float* sh_gate = (const float*)d_in[10];
  const float* sh_up = (const float*)d_in[11];
  const float* sh_down = (const float*)d_in[12];

  float* out = (float*)d_out;             // T*H
  float* resid = out + (size_t)T * H;     // T*H (second output)

  float* ws = (float*)d_ws;
  float* h1 = ws;                          // T*H   (later: shared-gate out)
  float* qkv = h1 + (size_t)T * H;         // T*QKVN
  float* ao = qkv + (size_t)T * QKVN;      // T*H   (later: shared-up out)
  float* h2 = ao + (size_t)T * H;          // T*H
  float* gb1 = h2 + (size_t)T * H;         // T*FF  (wo temp / expert gate out / g)
  float* gb2 = gb1 + (size_t)T * FF;       // T*FF  (expert up out)
  float* xg = gb2 + (size_t)T * FF;        // T*H   (gathered x_in)
  float* outp = xg + (size_t)T * H;        // T*H   (permuted expert out)
  int* counts = (int*)(outp + (size_t)T * H); // NE
  int* cnt2 = counts + NE;                 // NE
  int* offs = cnt2 + NE;                   // NE+1
  int* idx = offs + NE + 1;                // T
  int* perm = idx + T;                     // T
  int* pos = perm + T;                     // T
  float* gate = (float*)(pos + T);         // T

  // 1. h1 = rmsnorm(hidden) * ln1_w
  rmsnorm1024<<<T, 256, 0, stream>>>(hidden, ln1_w, h1);
  // 2. qkv = h1 @ wqkv
  gemm64<<<dim3(QKVN / BN, T / BM, 1), 256, 0, stream>>>(h1, wqkv, qkv, T, QKVN, H, nullptr, 0);
  // 3. RoPE + q/k rmsnorm in place
  rope_norm_kernel<<<T * (NH + NKV), 64, 0, stream>>>(qkv, positions);
  // 4. attention -> ao
  attn_kernel<<<dim3(T / 64, NH), 256, 0, stream>>>(qkv, ao);
  // 5. gb1 = ao @ wo
  gemm64<<<dim3(H / BN, T / BM, 1), 256, 0, stream>>>(ao, wo, gb1, T, H, NH * DH, nullptr, 0);
  // 6. resid = gb1 + hidden
  add_kernel<<<(T * H / 4 + 255) / 256, 256, 0, stream>>>(gb1, hidden, resid, T * H / 4);
  // 7. h2 = rmsnorm(resid) * ln2_w
  rmsnorm1024<<<T, 256, 0, stream>>>(resid, ln2_w, h2);
  // 8. zero counts + cnt2
  zero_counts_kernel<<<1, 64, 0, stream>>>(counts);
  // 9. router: idx, gate, counts
  router_kernel<<<T, 64, 0, stream>>>(h2, router_w, idx, gate, counts);
  // 10. exclusive scan of counts
  scan_kernel<<<1, 64, 0, stream>>>(counts, offs);
  // 11. token -> permuted position
  assign_kernel<<<T / 256, 256, 0, stream>>>(idx, offs, cnt2, perm, pos);
  // 12. gather xg[p] = h2[perm[p]] * gate[perm[p]]
  gather_kernel<<<T, 256, 0, stream>>>(h2, gate, perm, xg);
  // 13/14. grouped expert gate/up GEMMs
  gemm64<<<dim3(FF / BN, T / BM, NE), 256, 0, stream>>>(xg, w_gate, gb1, T, FF, H, offs, (long long)H * FF);
  gemm64<<<dim3(FF / BN, T / BM, NE), 256, 0, stream>>>(xg, w_up, gb2, T, FF, H, offs, (long long)H * FF);
  // 15. gb1 = silu(gb1) * gb2
  silumul_kernel<<<(T * FF / 4 + 255) / 256, 256, 0, stream>>>(gb1, gb2, T * FF / 4);
  // 16. outp = gb1 @ w_down[e] (grouped)
  gemm64<<<dim3(H / BN, T / BM, NE), 256, 0, stream>>>(gb1, w_down, outp, T, H, FF, offs, (long long)FF * H);
  // 17-20. shared expert -> out
  gemm64<<<dim3(FF / BN, T / BM, 1), 256, 0, stream>>>(h2, sh_gate, h1, T, FF, H, nullptr, 0);
  gemm64<<<dim3(FF / BN, T / BM, 1), 256, 0, stream>>>(h2, sh_up, ao, T, FF, H, nullptr, 0);
  silumul_kernel<<<(T * FF / 4 + 255) / 256, 256, 0, stream>>>(h1, ao, T * FF / 4);
  gemm64<<<dim3(H / BN, T / BM, 1), 256, 0, stream>>>(h1, sh_down, out, T, H, FF, nullptr, 0);
  // 21. out += routed (scatter back via pos)
  final_add_kernel<<<T, 256, 0, stream>>>(out, outp, pos);
}

// Round 2
// 882.260 us; speedup vs baseline: 1.8537x; 1.8537x over previous
//
#include <hip/hip_runtime.h>
#include <hip/hip_bf16.h>
#include <cmath>
#include <cstdint>

#define T 2048
#define H 1024
#define NH 16
#define NKV 4
#define DH 64
#define NE 8
#define FF 1024
#define QKVN ((NH + 2 * NKV) * DH) /* 1536 */
#define EPS 1e-5f
#define ROPE_THETA 500000.0f
#define ATTN_SCALE 0.125f

typedef short bf16x8 __attribute__((ext_vector_type(8)));
typedef float floatx4 __attribute__((ext_vector_type(4)));
typedef float f4 __attribute__((ext_vector_type(4)));

__device__ __forceinline__ void gload16(const void* g, void* l) {
  __builtin_amdgcn_global_load_lds((const __attribute__((address_space(1))) void*)g,
                                   (__attribute__((address_space(3))) void*)l, 16, 0, 0);
}

// ---------------- rmsnorm rows of 1024; optional fp32 and bf16 outputs ------
__global__ __launch_bounds__(256) void rmsnorm1024(const float* __restrict__ x,
                                                   const float* __restrict__ w,
                                                   float* __restrict__ yf,
                                                   __hip_bfloat16* __restrict__ yb) {
  int row = blockIdx.x;
  const float4* x4 = (const float4*)(x + (size_t)row * H);
  float4 v = x4[threadIdx.x];
  float s = v.x * v.x + v.y * v.y + v.z * v.z + v.w * v.w;
  #pragma unroll
  for (int o = 32; o; o >>= 1) s += __shfl_down(s, o, 64);
  __shared__ float red[4];
  if ((threadIdx.x & 63) == 0) red[threadIdx.x >> 6] = s;
  __syncthreads();
  s = red[0] + red[1] + red[2] + red[3];
  float inv = rsqrtf(s * (1.0f / (float)H) + EPS);
  float4 wv = ((const float4*)w)[threadIdx.x];
  float o0 = v.x * inv * wv.x, o1 = v.y * inv * wv.y, o2 = v.z * inv * wv.z, o3 = v.w * inv * wv.w;
  if (yf) {
    float4 o4 = make_float4(o0, o1, o2, o3);
    ((float4*)(yf + (size_t)row * H))[threadIdx.x] = o4;
  }
  if (yb) {
    __hip_bfloat16* yp = yb + (size_t)row * H + threadIdx.x * 4;
    yp[0] = __float2bfloat16(o0);
    yp[1] = __float2bfloat16(o1);
    yp[2] = __float2bfloat16(o2);
    yp[3] = __float2bfloat16(o3);
  }
}

// ---------------- fp32 [R][C] -> bf16 [C][R] transpose+cast ----------------
__global__ __launch_bounds__(256) void tcast(const float* __restrict__ src,
                                             __hip_bfloat16* __restrict__ dst, int R, int C,
                                             long long sStride, long long dStride) {
  src += (long long)blockIdx.z * sStride;
  dst += (long long)blockIdx.z * dStride;
  int c0 = blockIdx.x * 32, r0 = blockIdx.y * 32;
  __shared__ float tile[32][33];
  int tc = threadIdx.x & 31, tr = threadIdx.x >> 5;
  #pragma unroll
  for (int i = 0; i < 4; i++)
    tile[tr + 8 * i][tc] = src[(long long)(r0 + tr + 8 * i) * C + c0 + tc];
  __syncthreads();
  #pragma unroll
  for (int i = 0; i < 4; i++)
    dst[(long long)(c0 + tr + 8 * i) * R + r0 + tc] = __float2bfloat16(tile[tc][tr + 8 * i]);
}

// ---------------- bf16 MFMA GEMM: C[M,N] = A[M,K] * Bt[N,K]^T ----------------
// 128x128 tile, BK=32, 4 waves (2x2), each wave 4x4 of 16x16x32 MFMA.
__global__ __launch_bounds__(256) void gemm_bf16(const __hip_bfloat16* __restrict__ A,
                                                 const __hip_bfloat16* __restrict__ Bt,
                                                 void* __restrict__ Cout, int M, int N, int K,
                                                 int out_bf16, const int* __restrict__ row_offs,
                                                 long long strideB) {
  int e = blockIdx.z;
  int rbeg = 0, rend = M;
  if (row_offs) { rbeg = row_offs[e]; rend = row_offs[e + 1]; }
  long long m0 = rbeg + (long long)blockIdx.y * 128;
  if (m0 >= rend) return;
  long long n0 = (long long)blockIdx.x * 128;
  const __hip_bfloat16* Bp = Bt + (long long)e * strideB;

  __shared__ unsigned short As[128 * 32];
  __shared__ unsigned short Bs[128 * 32];

  int tid = threadIdx.x;
  int lane = tid & 63, w = tid >> 6;
  int wr = (w >> 1) * 64, wc = (w & 1) * 64;
  int qd = lane >> 4, ln16 = lane & 15;

  floatx4 acc[4][4];
  floatx4 zero = {0.f, 0.f, 0.f, 0.f};
  #pragma unroll
  for (int i = 0; i < 4; i++)
    #pragma unroll
    for (int j = 0; j < 4; j++) acc[i][j] = zero;

  int fe = tid * 8;           // flat element offset for issue 0
  int row0 = tid >> 2;        // fe/32
  int ko0 = (tid & 3) << 3;   // fe%32

  for (int k0 = 0; k0 < K; k0 += 32) {
    long long ra0 = m0 + row0;       if (ra0 >= rend) ra0 = rend - 1;
    long long ra1 = m0 + row0 + 64;  if (ra1 >= rend) ra1 = rend - 1;
    gload16(A + ra0 * K + k0 + ko0, As + fe);
    gload16(A + ra1 * K + k0 + ko0, As + fe + 2048);
    gload16(Bp + (n0 + row0) * K + k0 + ko0, Bs + fe);
    gload16(Bp + (n0 + row0 + 64) * K + k0 + ko0, Bs + fe + 2048);
    __syncthreads();
    bf16x8 af[4], bfr[4];
    #pragma unroll
    for (int i = 0; i < 4; i++)
      af[i] = *(const bf16x8*)(As + (wr + i * 16 + ln16) * 32 + qd * 8);
    #pragma unroll
    for (int j = 0; j < 4; j++)
      bfr[j] = *(const bf16x8*)(Bs + (wc + j * 16 + ln16) * 32 + qd * 8);
    #pragma unroll
    for (int i = 0; i < 4; i++)
      #pragma unroll
      for (int j = 0; j < 4; j++)
        acc[i][j] = __builtin_amdgcn_mfma_f32_16x16x32_bf16(af[i], bfr[j], acc[i][j], 0, 0, 0);
    __syncthreads();
  }

  #pragma unroll
  for (int i = 0; i < 4; i++) {
    #pragma unroll
    for (int r = 0; r < 4; r++) {
      long long gm = m0 + wr + i * 16 + qd * 4 + r;
      if (gm < rend) {
        #pragma unroll
        for (int j = 0; j < 4; j++) {
          long long gn = n0 + wc + j * 16 + ln16;
          float v = acc[i][j][r];
          if (out_bf16)
            ((__hip_bfloat16*)Cout)[gm * N + gn] = __float2bfloat16(v);
          else
            ((float*)Cout)[gm * N + gn] = v;
        }
      }
    }
  }
}

// ---------------- RoPE + per-head rmsnorm on q,k (in place, fp32) ----------
__global__ __launch_bounds__(64) void rope_norm_kernel(float* __restrict__ qkv,
                                                       const int* __restrict__ positions) {
  int b = blockIdx.x;
  int t = b / (NH + NKV);
  int hh = b % (NH + NKV);
  float* ptr = qkv + (long long)t * QKVN + ((hh < NH) ? hh * DH : NH * DH + (hh - NH) * DH);
  int d = threadIdx.x;
  float v = ptr[d];
  int fi = d & 31;
  float inv_freq = __powf(ROPE_THETA, -(float)fi / 32.0f);
  float ang = (float)positions[t] * inv_freq;
  float c = cosf(ang), s = sinf(ang);
  float other = __shfl_xor(v, 32, 64);
  float r = (d < 32) ? (v * c - other * s) : (v * c + other * s);
  float sq = r * r;
  #pragma unroll
  for (int off = 32; off; off >>= 1) sq += __shfl_xor(sq, off, 64);
  ptr[d] = r * rsqrtf(sq * (1.0f / (float)DH) + EPS);
}

// ---------------- causal flash attention (fp32, deferred rescale) ----------
__global__ __launch_bounds__(256) void attn_kernel(const float* __restrict__ qkv,
                                                   __hip_bfloat16* __restrict__ ao) {
  int h = blockIdx.y;
  int tile0 = blockIdx.x * 64;
  int lane = threadIdx.x & 63;
  int g = threadIdx.x >> 6;
  int t = tile0 + lane;
  int kvh = h >> 2;

  const float* qrow = qkv + (long long)t * QKVN + h * DH;
  f4 Q[16], O[16];
  f4 zf = {0.f, 0.f, 0.f, 0.f};
  #pragma unroll
  for (int d4 = 0; d4 < 16; d4++) {
    f4 qv = *(const f4*)(qrow + d4 * 4);
    Q[d4] = qv * ATTN_SCALE;
    O[d4] = zf;
  }
  float m = -1e30f, l = 0.f;

  __shared__ float Ks[32][DH];
  __shared__ float Vs[32][DH];

  int kmax = tile0 + 64;
  for (int kb = 0; kb < kmax; kb += 32) {
    int tid = threadIdx.x;
    #pragma unroll
    for (int it = 0; it < 2; it++) {
      int idx4 = tid + it * 256;
      int j = idx4 >> 4;
      int dd = (idx4 & 15) << 2;
      long long rowb = (long long)(kb + j) * QKVN + kvh * DH + dd;
      *(float4*)&Ks[j][dd] = *(const float4*)(qkv + rowb + NH * DH);
      *(float4*)&Vs[j][dd] = *(const float4*)(qkv + rowb + (NH + NKV) * DH);
    }
    __syncthreads();

    float sv[8];
    #pragma unroll
    for (int j2 = 0; j2 < 8; j2++) {
      int j = g * 8 + j2;
      f4 a0 = zf, a1 = zf;
      #pragma unroll
      for (int d4 = 0; d4 < 16; d4 += 2) {
        a0 += Q[d4] * (*(const f4*)&Ks[j][d4 * 4]);
        a1 += Q[d4 + 1] * (*(const f4*)&Ks[j][d4 * 4 + 4]);
      }
      f4 at = a0 + a1;
      float s = at.x + at.y + at.z + at.w;
      sv[j2] = (kb + j <= t) ? s : -1e30f;
    }
    float ms = sv[0];
    #pragma unroll
    for (int j2 = 1; j2 < 8; j2++) ms = fmaxf(ms, sv[j2]);
    float mn = fmaxf(m, ms);
    float alpha = __expf(m - mn);
    float p[8], ps = 0.f;
    #pragma unroll
    for (int j2 = 0; j2 < 8; j2++) {
      p[j2] = (kb + g * 8 + j2 <= t) ? __expf(sv[j2] - mn) : 0.f;
      ps += p[j2];
    }
    l = l * alpha + ps;
    m = mn;
    #pragma unroll
    for (int d4 = 0; d4 < 16; d4++) {
      f4 o = O[d4] * alpha;
      #pragma unroll
      for (int j2 = 0; j2 < 8; j2++) o += p[j2] * (*(const f4*)&Vs[g * 8 + j2][d4 * 4]);
      O[d4] = o;
    }
    __syncthreads();
  }

  __shared__ float mred[4][64], lred[4][64];
  mred[g][lane] = m;
  lred[g][lane] = l;
  __syncthreads();
  float mstar = fmaxf(fmaxf(mred[0][lane], mred[1][lane]), fmaxf(mred[2][lane], mred[3][lane]));
  float lstar = 0.f;
  #pragma unroll
  for (int gg = 0; gg < 4; gg++) lstar += lred[gg][lane] * __expf(mred[gg][lane] - mstar);
  float f = __expf(m - mstar);
  __shared__ float Obuf[64][DH + 1];
  for (int gg = 0; gg < 4; gg++) {
    if (g == gg) {
      #pragma unroll
      for (int d4 = 0; d4 < 16; d4++) {
        f4 o = O[d4] * f;
        if (gg == 0) {
          Obuf[lane][d4 * 4 + 0] = o.x; Obuf[lane][d4 * 4 + 1] = o.y;
          Obuf[lane][d4 * 4 + 2] = o.z; Obuf[lane][d4 * 4 + 3] = o.w;
        } else {
          Obuf[lane][d4 * 4 + 0] += o.x; Obuf[lane][d4 * 4 + 1] += o.y;
          Obuf[lane][d4 * 4 + 2] += o.z; Obuf[lane][d4 * 4 + 3] += o.w;
        }
      }
    }
    __syncthreads();
  }
  float invl = 1.0f / lstar;
  #pragma unroll
  for (int i = 0; i < 16; i++) {
    int d = g * 16 + i;
    ao[(long long)t * (NH * DH) + h * DH + d] = __float2bfloat16(Obuf[lane][d] * invl);
  }
}

// ---------------- elementwise helpers ----------------
__global__ void add_kernel(const float* __restrict__ a, const float* __restrict__ b,
                           float* __restrict__ y, int n4) {
  int i = blockIdx.x * blockDim.x + threadIdx.x;
  if (i >= n4) return;
  float4 av = ((const float4*)a)[i];
  float4 bv = ((const float4*)b)[i];
  av.x += bv.x; av.y += bv.y; av.z += bv.z; av.w += bv.w;
  ((float4*)y)[i] = av;
}

__global__ void silumul_bf16(const __hip_bfloat16* __restrict__ a,
                             const __hip_bfloat16* __restrict__ b,
                             __hip_bfloat16* __restrict__ y, int n4) {
  int i = blockIdx.x * blockDim.x + threadIdx.x;
  if (i >= n4) return;
  #pragma unroll
  for (int k = 0; k < 4; k++) {
    float av = __bfloat162float(a[i * 4 + k]);
    float bv = __bfloat162float(b[i * 4 + k]);
    float s = av / (1.f + __expf(-av)) * bv;
    y[i * 4 + k] = __float2bfloat16(s);
  }
}

// ---------------- router (top-1 + sigmoid gate), fp32 ----------------
__global__ __launch_bounds__(64) void router_kernel(const float* __restrict__ h2,
                                                    const float* __restrict__ rw,
                                                    int* __restrict__ idx,
                                                    float* __restrict__ gate,
                                                    int* __restrict__ counts) {
  int t = blockIdx.x;
  int lane = threadIdx.x;
  float acc[NE] = {};
  for (int k = lane; k < H; k += 64) {
    float hv = h2[(long long)t * H + k];
    float4 r0 = *(const float4*)(rw + (long long)k * NE);
    float4 r1 = *(const float4*)(rw + (long long)k * NE + 4);
    acc[0] += hv * r0.x; acc[1] += hv * r0.y; acc[2] += hv * r0.z; acc[3] += hv * r0.w;
    acc[4] += hv * r1.x; acc[5] += hv * r1.y; acc[6] += hv * r1.z; acc[7] += hv * r1.w;
  }
  #pragma unroll
  for (int off = 32; off; off >>= 1)
    #pragma unroll
    for (int e2 = 0; e2 < NE; e2++) acc[e2] += __shfl_down(acc[e2], off, 64);
  if (lane == 0) {
    int best = 0;
    float bv = acc[0];
    #pragma unroll
    for (int e2 = 1; e2 < NE; e2++)
      if (acc[e2] > bv) { bv = acc[e2]; best = e2; }
    idx[t] = best;
    gate[t] = 1.f / (1.f + expf(-bv));
    atomicAdd(&counts[best], 1);
  }
}

__global__ void zero_counts_kernel(int* c) {
  if (threadIdx.x < 2 * NE) c[threadIdx.x] = 0;
}

__global__ void scan_kernel(const int* __restrict__ counts, int* __restrict__ offs) {
  if (threadIdx.x == 0) {
    int s = 0;
    for (int e2 = 0; e2 < NE; e2++) { offs[e2] = s; s += counts[e2]; }
    offs[NE] = s;
  }
}

__global__ void assign_kernel(const int* __restrict__ idx, const int* __restrict__ offs,
                              int* __restrict__ cnt2, int* __restrict__ perm,
                              int* __restrict__ pos) {
  int t = blockIdx.x * blockDim.x + threadIdx.x;
  if (t >= T) return;
  int e2 = idx[t];
  int p = offs[e2] + atomicAdd(&cnt2[e2], 1);
  pos[t] = p;
  perm[p] = t;
}

__global__ __launch_bounds__(256) void gather_kernel(const float* __restrict__ h2,
                                                     const float* __restrict__ gate,
                                                     const int* __restrict__ perm,
                                                     __hip_bfloat16* __restrict__ xg) {
  int p = blockIdx.x;
  int t = perm[p];
  float g = gate[t];
  float4 v = ((const float4*)(h2 + (long long)t * H))[threadIdx.x];
  __hip_bfloat16* yp = xg + (long long)p * H + threadIdx.x * 4;
  yp[0] = __float2bfloat16(v.x * g);
  yp[1] = __float2bfloat16(v.y * g);
  yp[2] = __float2bfloat16(v.z * g);
  yp[3] = __float2bfloat16(v.w * g);
}

__global__ __launch_bounds__(256) void final_add_kernel(float* __restrict__ out,
                                                        const float* __restrict__ outp,
                                                        const int* __restrict__ pos) {
  int t = blockIdx.x;
  int p = pos[t];
  const float4* src = (const float4*)(outp + (long long)p * H);
  float4* dst = (float4*)(out + (long long)t * H);
  float4 a = dst[threadIdx.x];
  float4 b = src[threadIdx.x];
  a.x += b.x; a.y += b.y; a.z += b.z; a.w += b.w;
  dst[threadIdx.x] = a;
}

// ---------------- launcher ----------------
extern "C" void kernel_launch(void* const* d_in, const int* in_sizes, int n_in,
                              void* d_out, int out_size, void* d_ws, size_t ws_size,
                              hipStream_t stream) {
  const int* positions = (const int*)d_in[0];
  const float* hidden = (const float*)d_in[1];
  const float* ln1_w = (const float*)d_in[2];
  const float* ln2_w = (const float*)d_in[3];
  const float* wqkv = (const float*)d_in[4];
  const float* wo = (const float*)d_in[5];
  const float* router_w = (const float*)d_in[6];
  const float* w_gate = (const float*)d_in[7];
  const float* w_up = (const float*)d_in[8];
  const float* w_down = (const float*)d_in[9];
  const float* sh_gate = (const float*)d_in[10];
  const float* sh_up = (const float*)d_in[11];
  const float* sh_down = (const float*)d_in[12];

  float* out = (float*)d_out;
  float* resid = out + (size_t)T * H;

  char* p = (char*)d_ws;
  auto alloc = [&](size_t bytes) { char* r = p; p += (bytes + 255) & ~(size_t)255; return r; };

  float* qkv = (float*)alloc((size_t)T * QKVN * 4);
  float* h2 = (float*)alloc((size_t)T * H * 4);
  float* gb1 = (float*)alloc((size_t)T * H * 4);     // wo out
  float* outp = (float*)alloc((size_t)T * H * 4);    // permuted expert out
  __hip_bfloat16* h1b = (__hip_bfloat16*)alloc((size_t)T * H * 2);
  __hip_bfloat16* aob = (__hip_bfloat16*)alloc((size_t)T * H * 2);
  __hip_bfloat16* h2b = (__hip_bfloat16*)alloc((size_t)T * H * 2);
  __hip_bfloat16* xgb = (__hip_bfloat16*)alloc((size_t)T * H * 2);
  __hip_bfloat16* gA = (__hip_bfloat16*)alloc((size_t)T * FF * 2);
  __hip_bfloat16* gB = (__hip_bfloat16*)alloc((size_t)T * FF * 2);
  __hip_bfloat16* gP = (__hip_bfloat16*)alloc((size_t)T * FF * 2);
  __hip_bfloat16* wqkvT = (__hip_bfloat16*)alloc((size_t)H * QKVN * 2);
  __hip_bfloat16* woT = (__hip_bfloat16*)alloc((size_t)H * H * 2);
  __hip_bfloat16* shgT = (__hip_bfloat16*)alloc((size_t)H * FF * 2);
  __hip_bfloat16* shuT = (__hip_bfloat16*)alloc((size_t)H * FF * 2);
  __hip_bfloat16* shdT = (__hip_bfloat16*)alloc((size_t)H * FF * 2);
  __hip_bfloat16* wgT = (__hip_bfloat16*)alloc((size_t)NE * H * FF * 2);
  __hip_bfloat16* wuT = (__hip_bfloat16*)alloc((size_t)NE * H * FF * 2);
  __hip_bfloat16* wdT = (__hip_bfloat16*)alloc((size_t)NE * H * FF * 2);
  int* counts = (int*)alloc(2 * NE * 4);  // counts + cnt2 contiguous
  int* cnt2 = counts + NE;
  int* offs = (int*)alloc((NE + 1) * 4);
  int* idx = (int*)alloc(T * 4);
  int* perm = (int*)alloc(T * 4);
  int* pos = (int*)alloc(T * 4);
  float* gate = (float*)alloc(T * 4);

  // weight transpose+cast (once per launch)
  tcast<<<dim3(QKVN / 32, H / 32, 1), 256, 0, stream>>>(wqkv, wqkvT, H, QKVN, 0, 0);
  tcast<<<dim3(H / 32, H / 32, 1), 256, 0, stream>>>(wo, woT, H, H, 0, 0);
  tcast<<<dim3(FF / 32, H / 32, 1), 256, 0, stream>>>(sh_gate, shgT, H, FF, 0, 0);
  tcast<<<dim3(FF / 32, H / 32, 1), 256, 0, stream>>>(sh_up, shuT, H, FF, 0, 0);
  tcast<<<dim3(H / 32, FF / 32, 1), 256, 0, stream>>>(sh_down, shdT, FF, H, 0, 0);
  tcast<<<dim3(FF / 32, H / 32, NE), 256, 0, stream>>>(w_gate, wgT, H, FF, (long long)H * FF, (long long)H * FF);
  tcast<<<dim3(FF / 32, H / 32, NE), 256, 0, stream>>>(w_up, wuT, H, FF, (long long)H * FF, (long long)H * FF);
  tcast<<<dim3(H / 32, FF / 32, NE), 256, 0, stream>>>(w_down, wdT, FF, H, (long long)FF * H, (long long)FF * H);

  // 1. h1b = bf16(rmsnorm(hidden) * ln1_w)
  rmsnorm1024<<<T, 256, 0, stream>>>(hidden, ln1_w, nullptr, h1b);
  // 2. qkv = h1 @ wqkv (fp32 out)
  gemm_bf16<<<dim3(QKVN / 128, T / 128, 1), 256, 0, stream>>>(h1b, wqkvT, qkv, T, QKVN, H, 0, nullptr, 0);
  // 3. RoPE + q/k rmsnorm
  rope_norm_kernel<<<T * (NH + NKV), 64, 0, stream>>>(qkv, positions);
  // 4. attention -> aob (bf16)
  attn_kernel<<<dim3(T / 64, NH), 256, 0, stream>>>(qkv, aob);
  // 5. gb1 = ao @ wo (fp32)
  gemm_bf16<<<dim3(H / 128, T / 128, 1), 256, 0, stream>>>(aob, woT, gb1, T, H, H, 0, nullptr, 0);
  // 6. resid = gb1 + hidden
  add_kernel<<<(T * H / 4 + 255) / 256, 256, 0, stream>>>(gb1, hidden, resid, T * H / 4);
  // 7. h2 (fp32) + h2b (bf16)
  rmsnorm1024<<<T, 256, 0, stream>>>(resid, ln2_w, h2, h2b);
  // 8-11. routing
  zero_counts_kernel<<<1, 64, 0, stream>>>(counts);
  router_kernel<<<T, 64, 0, stream>>>(h2, router_w, idx, gate, counts);
  scan_kernel<<<1, 64, 0, stream>>>(counts, offs);
  assign_kernel<<<T / 256, 256, 0, stream>>>(idx, offs, cnt2, perm, pos);
  // 12. gather xgb[p] = bf16(h2[perm[p]] * gate)
  gather_kernel<<<T, 256, 0, stream>>>(h2, gate, perm, xgb);
  // 13/14. grouped expert gate/up GEMMs (bf16 out)
  gemm_bf16<<<dim3(FF / 128, T / 128, NE), 256, 0, stream>>>(xgb, wgT, gA, T, FF, H, 1, offs, (long long)H * FF);
  gemm_bf16<<<dim3(FF / 128, T / 128, NE), 256, 0, stream>>>(xgb, wuT, gB, T, FF, H, 1, offs, (long long)H * FF);
  // 15. gP = silu(gA) * gB
  silumul_bf16<<<(T * FF / 4 + 255) / 256, 256, 0, stream>>>(gA, gB, gP, T * FF / 4);
  // 16. outp = gP @ w_down[e] (fp32 out)
  gemm_bf16<<<dim3(H / 128, T / 128, NE), 256, 0, stream>>>(gP, wdT, outp, T, H, FF, 0, offs, (long long)FF * H);
  // 17-20. shared expert
  gemm_bf16<<<dim3(FF / 128, T / 128, 1), 256, 0, stream>>>(h2b, shgT, gA, T, FF, H, 1, nullptr, 0);
  gemm_bf16<<<dim3(FF / 128, T / 128, 1), 256, 0, stream>>>(h2b, shuT, gB, T, FF, H, 1, nullptr, 0);
  silumul_bf16<<<(T * FF / 4 + 255) / 256, 256, 0, stream>>>(gA, gB, gP, T * FF / 4);
  gemm_bf16<<<dim3(H / 128, T / 128, 1), 256, 0, stream>>>(gP, shdT, out, T, H, FF, 0, nullptr, 0);
  // 21. out += routed
  final_add_kernel<<<T, 256, 0, stream>>>(out, outp, pos);
}

// Round 3
// 612.419 us; speedup vs baseline: 2.6705x; 1.4406x over previous
//
#include <hip/hip_runtime.h>
#include <hip/hip_bf16.h>
#include <cmath>
#include <cstdint>

#define T 2048
#define H 1024
#define NH 16
#define NKV 4
#define DH 64
#define NE 8
#define FF 1024
#define QKVN ((NH + 2 * NKV) * DH) /* 1536 */
#define EPS 1e-5f
#define ATTN_SCALE 0.125f

typedef short bf16x8 __attribute__((ext_vector_type(8)));
typedef float floatx4 __attribute__((ext_vector_type(4)));
typedef float f4 __attribute__((ext_vector_type(4)));

__device__ __forceinline__ void gload16(const void* g, void* l) {
  __builtin_amdgcn_global_load_lds((const __attribute__((address_space(1))) void*)g,
                                   (__attribute__((address_space(3))) void*)l, 16, 0, 0);
}

// ---------------- rmsnorm rows of 1024; optional fp32 and bf16 outputs ------
__global__ __launch_bounds__(256) void rmsnorm1024(const float* __restrict__ x,
                                                   const float* __restrict__ w,
                                                   float* __restrict__ yf,
                                                   __hip_bfloat16* __restrict__ yb) {
  int row = blockIdx.x;
  const float4* x4 = (const float4*)(x + (size_t)row * H);
  float4 v = x4[threadIdx.x];
  float s = v.x * v.x + v.y * v.y + v.z * v.z + v.w * v.w;
  #pragma unroll
  for (int o = 32; o; o >>= 1) s += __shfl_down(s, o, 64);
  __shared__ float red[4];
  if ((threadIdx.x & 63) == 0) red[threadIdx.x >> 6] = s;
  __syncthreads();
  s = red[0] + red[1] + red[2] + red[3];
  float inv = rsqrtf(s * (1.0f / (float)H) + EPS);
  float4 wv = ((const float4*)w)[threadIdx.x];
  float o0 = v.x * inv * wv.x, o1 = v.y * inv * wv.y, o2 = v.z * inv * wv.z, o3 = v.w * inv * wv.w;
  if (yf) {
    float4 o4 = make_float4(o0, o1, o2, o3);
    ((float4*)(yf + (size_t)row * H))[threadIdx.x] = o4;
  }
  if (yb) {
    __hip_bfloat16* yp = yb + (size_t)row * H + threadIdx.x * 4;
    yp[0] = __float2bfloat16(o0);
    yp[1] = __float2bfloat16(o1);
    yp[2] = __float2bfloat16(o2);
    yp[3] = __float2bfloat16(o3);
  }
}

// ------- fp32 [R][C] (row stride srcStride) -> bf16 [C][R] (row stride dstStride) -------
__global__ __launch_bounds__(256) void tcast(const float* __restrict__ src,
                                             __hip_bfloat16* __restrict__ dst, int R, int C,
                                             long long srcStride, long long dstStride,
                                             long long sBatch, long long dBatch) {
  src += (long long)blockIdx.z * sBatch;
  dst += (long long)blockIdx.z * dBatch;
  int c0 = blockIdx.x * 32, r0 = blockIdx.y * 32;
  __shared__ float tile[32][33];
  int tc = threadIdx.x & 31, tr = threadIdx.x >> 5;
  #pragma unroll
  for (int i = 0; i < 4; i++)
    tile[tr + 8 * i][tc] = src[(long long)(r0 + tr + 8 * i) * srcStride + c0 + tc];
  __syncthreads();
  #pragma unroll
  for (int i = 0; i < 4; i++)
    dst[(long long)(c0 + tr + 8 * i) * dstStride + r0 + tc] = __float2bfloat16(tile[tc][tr + 8 * i]);
}

// ---------------- bf16 MFMA GEMM: C[M,N] = A[M,K] * Bt[N,K]^T ----------------
__global__ __launch_bounds__(256) void gemm_bf16(const __hip_bfloat16* __restrict__ A,
                                                 const __hip_bfloat16* __restrict__ Bt,
                                                 void* __restrict__ Cout, int M, int N, int K,
                                                 int out_bf16, const int* __restrict__ row_offs,
                                                 long long strideB) {
  int e = blockIdx.z;
  int rbeg = 0, rend = M;
  if (row_offs) { rbeg = row_offs[e]; rend = row_offs[e + 1]; }
  long long m0 = rbeg + (long long)blockIdx.y * 128;
  if (m0 >= rend) return;
  long long n0 = (long long)blockIdx.x * 128;
  const __hip_bfloat16* Bp = Bt + (long long)e * strideB;

  __shared__ unsigned short As[128 * 32];
  __shared__ unsigned short Bs[128 * 32];

  int tid = threadIdx.x;
  int lane = tid & 63, w = tid >> 6;
  int wr = (w >> 1) * 64, wc = (w & 1) * 64;
  int qd = lane >> 4, ln16 = lane & 15;

  floatx4 acc[4][4];
  floatx4 zero = {0.f, 0.f, 0.f, 0.f};
  #pragma unroll
  for (int i = 0; i < 4; i++)
    #pragma unroll
    for (int j = 0; j < 4; j++) acc[i][j] = zero;

  int fe = tid * 8;
  int row0 = tid >> 2;
  int ko0 = (tid & 3) << 3;

  for (int k0 = 0; k0 < K; k0 += 32) {
    long long ra0 = m0 + row0;       if (ra0 >= rend) ra0 = rend - 1;
    long long ra1 = m0 + row0 + 64;  if (ra1 >= rend) ra1 = rend - 1;
    gload16(A + ra0 * K + k0 + ko0, As + fe);
    gload16(A + ra1 * K + k0 + ko0, As + fe + 2048);
    gload16(Bp + (n0 + row0) * K + k0 + ko0, Bs + fe);
    gload16(Bp + (n0 + row0 + 64) * K + k0 + ko0, Bs + fe + 2048);
    __syncthreads();
    bf16x8 af[4], bfr[4];
    #pragma unroll
    for (int i = 0; i < 4; i++)
      af[i] = *(const bf16x8*)(As + (wr + i * 16 + ln16) * 32 + qd * 8);
    #pragma unroll
    for (int j = 0; j < 4; j++)
      bfr[j] = *(const bf16x8*)(Bs + (wc + j * 16 + ln16) * 32 + qd * 8);
    #pragma unroll
    for (int i = 0; i < 4; i++)
      #pragma unroll
      for (int j = 0; j < 4; j++)
        acc[i][j] = __builtin_amdgcn_mfma_f32_16x16x32_bf16(af[i], bfr[j], acc[i][j], 0, 0, 0);
    __syncthreads();
  }

  #pragma unroll
  for (int i = 0; i < 4; i++) {
    #pragma unroll
    for (int r = 0; r < 4; r++) {
      long long gm = m0 + wr + i * 16 + qd * 4 + r;
      if (gm < rend) {
        #pragma unroll
        for (int j = 0; j < 4; j++) {
          long long gn = n0 + wc + j * 16 + ln16;
          float v = acc[i][j][r];
          if (out_bf16)
            ((__hip_bfloat16*)Cout)[gm * N + gn] = __float2bfloat16(v);
          else
            ((float*)Cout)[gm * N + gn] = v;
        }
      }
    }
  }
}

// ---------------- RoPE + per-head rmsnorm on q,k (in place, fp32) ----------
__global__ __launch_bounds__(256) void rope_norm_kernel(float* __restrict__ qkv,
                                                        const int* __restrict__ positions) {
  int b = blockIdx.x * 4 + (threadIdx.x >> 6);
  int t = b / (NH + NKV);
  int hh = b % (NH + NKV);
  float* ptr = qkv + (long long)t * QKVN + hh * DH;  // q heads then k heads contiguous
  int d = threadIdx.x & 63;
  float v = ptr[d];
  int fi = d & 31;
  // inv_freq = theta^(-fi/32) = exp2(-fi * log2(theta)/32), log2(5e5)=18.93156857
  float inv_freq = exp2f(-(float)fi * (18.93156857f / 32.0f));
  float ang = (float)positions[t] * inv_freq;
  float c = __cosf(ang), s = __sinf(ang);
  float other = __shfl_xor(v, 32, 64);
  float r = (d < 32) ? (v * c - other * s) : (v * c + other * s);
  float sq = r * r;
  #pragma unroll
  for (int off = 32; off; off >>= 1) sq += __shfl_xor(sq, off, 64);
  ptr[d] = r * rsqrtf(sq * (1.0f / (float)DH) + EPS);
}

// ---------------- pack q (scaled) and k to bf16 ----------------
__global__ __launch_bounds__(256) void pack_qk(const float* __restrict__ qkv,
                                               __hip_bfloat16* __restrict__ Qb,
                                               __hip_bfloat16* __restrict__ Kb) {
  int i = blockIdx.x * blockDim.x + threadIdx.x;  // float4 index over T*1280
  int t = i / 320;
  int c = (i - t * 320) * 4;
  float4 v = *(const float4*)(qkv + (size_t)t * QKVN + c);
  if (c < NH * DH) {
    __hip_bfloat16* yp = Qb + (size_t)t * (NH * DH) + c;
    yp[0] = __float2bfloat16(v.x * ATTN_SCALE);
    yp[1] = __float2bfloat16(v.y * ATTN_SCALE);
    yp[2] = __float2bfloat16(v.z * ATTN_SCALE);
    yp[3] = __float2bfloat16(v.w * ATTN_SCALE);
  } else {
    __hip_bfloat16* yp = Kb + (size_t)t * (NKV * DH) + (c - NH * DH);
    yp[0] = __float2bfloat16(v.x);
    yp[1] = __float2bfloat16(v.y);
    yp[2] = __float2bfloat16(v.z);
    yp[3] = __float2bfloat16(v.w);
  }
}

// ---------------- MFMA flash attention ----------------
// grid (T/64, NH), block 256 (4 waves x 16 q-rows). K-tiles of 64 in LDS.
__global__ __launch_bounds__(256) void attn_mfma(const __hip_bfloat16* __restrict__ Qb,
                                                 const __hip_bfloat16* __restrict__ Kb,
                                                 const __hip_bfloat16* __restrict__ VtG,
                                                 __hip_bfloat16* __restrict__ ao) {
  int h = blockIdx.y;
  int kvh = h >> 2;
  int nb = gridDim.x;
  int bx = blockIdx.x;
  int qi = (bx & 1) ? (nb - 1 - (bx >> 1)) : (bx >> 1);  // heavy/light interleave
  int q0 = qi * 64;

  __shared__ unsigned short Ks[64 * 64];
  __shared__ unsigned short Vs[64 * 64];       // V^T tile: [d][k]
  __shared__ unsigned short Ps[4 * 16 * 72];   // per-wave P: [16][72]

  int tid = threadIdx.x;
  int lane = tid & 63, w = tid >> 6;
  int qd = lane >> 4, ln16 = lane & 15;
  unsigned short* Pw = Ps + w * 16 * 72;

  // staging coords
  int r0 = tid >> 3;
  int c0 = (tid & 7) * 8;

  // Q fragments (held in registers for the whole kernel)
  int tq = q0 + w * 16 + ln16;
  const unsigned short* qp = (const unsigned short*)Qb + (size_t)tq * (NH * DH) + h * DH;
  bf16x8 aq[2];
  aq[0] = *(const bf16x8*)(qp + qd * 8);
  aq[1] = *(const bf16x8*)(qp + 32 + qd * 8);

  floatx4 O_[4];
  floatx4 zero = {0.f, 0.f, 0.f, 0.f};
  #pragma unroll
  for (int j = 0; j < 4; j++) O_[j] = zero;
  float m_[4] = {-1e30f, -1e30f, -1e30f, -1e30f};
  float l_[4] = {0.f, 0.f, 0.f, 0.f};
  int tq_base = q0 + w * 16 + qd * 4;

  for (int kb = 0; kb < q0 + 64; kb += 64) {
    gload16((const unsigned short*)Kb + (size_t)(kb + r0) * (NKV * DH) + kvh * DH + c0, Ks + tid * 8);
    gload16((const unsigned short*)Kb + (size_t)(kb + r0 + 32) * (NKV * DH) + kvh * DH + c0, Ks + tid * 8 + 2048);
    gload16((const unsigned short*)VtG + (size_t)(kvh * DH + r0) * T + kb + c0, Vs + tid * 8);
    gload16((const unsigned short*)VtG + (size_t)(kvh * DH + r0 + 32) * T + kb + c0, Vs + tid * 8 + 2048);
    __syncthreads();

    // S = Q K^T  (16 x 64 per wave)
    floatx4 S_[4];
    #pragma unroll
    for (int j = 0; j < 4; j++) S_[j] = zero;
    #pragma unroll
    for (int s = 0; s < 2; s++) {
      bf16x8 bk[4];
      #pragma unroll
      for (int j = 0; j < 4; j++)
        bk[j] = *(const bf16x8*)(Ks + (j * 16 + ln16) * 64 + s * 32 + qd * 8);
      #pragma unroll
      for (int j = 0; j < 4; j++)
        S_[j] = __builtin_amdgcn_mfma_f32_16x16x32_bf16(aq[s], bk[j], S_[j], 0, 0, 0);
    }

    // mask + online softmax (rows distributed: row = qd*4+r, col = j*16+ln16)
    float mx[4] = {-1e30f, -1e30f, -1e30f, -1e30f};
    #pragma unroll
    for (int j = 0; j < 4; j++) {
      int tk = kb + j * 16 + ln16;
      #pragma unroll
      for (int r = 0; r < 4; r++) {
        float sv = (tk <= tq_base + r) ? S_[j][r] : -1e30f;
        S_[j][r] = sv;
        mx[r] = fmaxf(mx[r], sv);
      }
    }
    #pragma unroll
    for (int off = 8; off; off >>= 1)
      #pragma unroll
      for (int r = 0; r < 4; r++) mx[r] = fmaxf(mx[r], __shfl_xor(mx[r], off, 64));
    float al[4], psum[4] = {0.f, 0.f, 0.f, 0.f};
    #pragma unroll
    for (int r = 0; r < 4; r++) {
      float mn = fmaxf(m_[r], mx[r]);
      al[r] = __expf(m_[r] - mn);
      m_[r] = mn;
    }
    #pragma unroll
    for (int j = 0; j < 4; j++)
      #pragma unroll
      for (int r = 0; r < 4; r++) {
        float pv = __expf(S_[j][r] - m_[r]);
        S_[j][r] = pv;
        psum[r] += pv;
      }
    #pragma unroll
    for (int off = 8; off; off >>= 1)
      #pragma unroll
      for (int r = 0; r < 4; r++) psum[r] += __shfl_xor(psum[r], off, 64);
    #pragma unroll
    for (int r = 0; r < 4; r++) l_[r] = l_[r] * al[r] + psum[r];

    // P -> per-wave LDS (bf16)
    #pragma unroll
    for (int j = 0; j < 4; j++)
      #pragma unroll
      for (int r = 0; r < 4; r++)
        ((__hip_bfloat16*)Pw)[(qd * 4 + r) * 72 + j * 16 + ln16] = __float2bfloat16(S_[j][r]);

    // O = O*alpha + P V
    #pragma unroll
    for (int j = 0; j < 4; j++)
      #pragma unroll
      for (int r = 0; r < 4; r++) O_[j][r] *= al[r];
    #pragma unroll
    for (int s = 0; s < 2; s++) {
      bf16x8 ap = *(const bf16x8*)(Pw + ln16 * 72 + s * 32 + qd * 8);
      bf16x8 bv[4];
      #pragma unroll
      for (int j = 0; j < 4; j++)
        bv[j] = *(const bf16x8*)(Vs + (j * 16 + ln16) * 64 + s * 32 + qd * 8);
      #pragma unroll
      for (int j = 0; j < 4; j++)
        O_[j] = __builtin_amdgcn_mfma_f32_16x16x32_bf16(ap, bv[j], O_[j], 0, 0, 0);
    }
    __syncthreads();
  }

  float inv[4];
  #pragma unroll
  for (int r = 0; r < 4; r++) inv[r] = 1.0f / l_[r];
  #pragma unroll
  for (int j = 0; j < 4; j++)
    #pragma unroll
    for (int r = 0; r < 4; r++)
      ao[(size_t)(tq_base + r) * (NH * DH) + h * DH + j * 16 + ln16] =
          __float2bfloat16(O_[j][r] * inv[r]);
}

// ---------------- elementwise helpers ----------------
__global__ void add_kernel(const float* __restrict__ a, const float* __restrict__ b,
                           float* __restrict__ y, int n4) {
  int i = blockIdx.x * blockDim.x + threadIdx.x;
  if (i >= n4) return;
  float4 av = ((const float4*)a)[i];
  float4 bv = ((const float4*)b)[i];
  av.x += bv.x; av.y += bv.y; av.z += bv.z; av.w += bv.w;
  ((float4*)y)[i] = av;
}

__global__ void silumul_bf16(const __hip_bfloat16* __restrict__ a,
                             const __hip_bfloat16* __restrict__ b,
                             __hip_bfloat16* __restrict__ y, int n4) {
  int i = blockIdx.x * blockDim.x + threadIdx.x;
  if (i >= n4) return;
  #pragma unroll
  for (int k = 0; k < 4; k++) {
    float av = __bfloat162float(a[i * 4 + k]);
    float bv = __bfloat162float(b[i * 4 + k]);
    float s = av / (1.f + __expf(-av)) * bv;
    y[i * 4 + k] = __float2bfloat16(s);
  }
}

// ---------------- router (top-1 + sigmoid gate), fp32 ----------------
__global__ __launch_bounds__(64) void router_kernel(const float* __restrict__ h2,
                                                    const float* __restrict__ rw,
                                                    int* __restrict__ idx,
                                                    float* __restrict__ gate,
                                                    int* __restrict__ counts) {
  int t = blockIdx.x;
  int lane = threadIdx.x;
  float acc[NE] = {};
  for (int k = lane; k < H; k += 64) {
    float hv = h2[(long long)t * H + k];
    float4 r0 = *(const float4*)(rw + (long long)k * NE);
    float4 r1 = *(const float4*)(rw + (long long)k * NE + 4);
    acc[0] += hv * r0.x; acc[1] += hv * r0.y; acc[2] += hv * r0.z; acc[3] += hv * r0.w;
    acc[4] += hv * r1.x; acc[5] += hv * r1.y; acc[6] += hv * r1.z; acc[7] += hv * r1.w;
  }
  #pragma unroll
  for (int off = 32; off; off >>= 1)
    #pragma unroll
    for (int e2 = 0; e2 < NE; e2++) acc[e2] += __shfl_down(acc[e2], off, 64);
  if (lane == 0) {
    int best = 0;
    float bv = acc[0];
    #pragma unroll
    for (int e2 = 1; e2 < NE; e2++)
      if (acc[e2] > bv) { bv = acc[e2]; best = e2; }
    idx[t] = best;
    gate[t] = 1.f / (1.f + expf(-bv));
    atomicAdd(&counts[best], 1);
  }
}

__global__ void zero_counts_kernel(int* c) {
  if (threadIdx.x < 2 * NE) c[threadIdx.x] = 0;
}

__global__ void scan_kernel(const int* __restrict__ counts, int* __restrict__ offs) {
  if (threadIdx.x == 0) {
    int s = 0;
    for (int e2 = 0; e2 < NE; e2++) { offs[e2] = s; s += counts[e2]; }
    offs[NE] = s;
  }
}

__global__ void assign_kernel(const int* __restrict__ idx, const int* __restrict__ offs,
                              int* __restrict__ cnt2, int* __restrict__ perm,
                              int* __restrict__ pos) {
  int t = blockIdx.x * blockDim.x + threadIdx.x;
  if (t >= T) return;
  int e2 = idx[t];
  int p = offs[e2] + atomicAdd(&cnt2[e2], 1);
  pos[t] = p;
  perm[p] = t;
}

__global__ __launch_bounds__(256) void gather_kernel(const float* __restrict__ h2,
                                                     const float* __restrict__ gate,
                                                     const int* __restrict__ perm,
                                                     __hip_bfloat16* __restrict__ xg) {
  int p = blockIdx.x;
  int t = perm[p];
  float g = gate[t];
  float4 v = ((const float4*)(h2 + (long long)t * H))[threadIdx.x];
  __hip_bfloat16* yp = xg + (long long)p * H + threadIdx.x * 4;
  yp[0] = __float2bfloat16(v.x * g);
  yp[1] = __float2bfloat16(v.y * g);
  yp[2] = __float2bfloat16(v.z * g);
  yp[3] = __float2bfloat16(v.w * g);
}

__global__ __launch_bounds__(256) void final_add_kernel(float* __restrict__ out,
                                                        const float* __restrict__ outp,
                                                        const int* __restrict__ pos) {
  int t = blockIdx.x;
  int p = pos[t];
  const float4* src = (const float4*)(outp + (long long)p * H);
  float4* dst = (float4*)(out + (long long)t * H);
  float4 a = dst[threadIdx.x];
  float4 b = src[threadIdx.x];
  a.x += b.x; a.y += b.y; a.z += b.z; a.w += b.w;
  dst[threadIdx.x] = a;
}

// ---------------- launcher ----------------
extern "C" void kernel_launch(void* const* d_in, const int* in_sizes, int n_in,
                              void* d_out, int out_size, void* d_ws, size_t ws_size,
                              hipStream_t stream) {
  const int* positions = (const int*)d_in[0];
  const float* hidden = (const float*)d_in[1];
  const float* ln1_w = (const float*)d_in[2];
  const float* ln2_w = (const float*)d_in[3];
  const float* wqkv = (const float*)d_in[4];
  const float* wo = (const float*)d_in[5];
  const float* router_w = (const float*)d_in[6];
  const float* w_gate = (const float*)d_in[7];
  const float* w_up = (const float*)d_in[8];
  const float* w_down = (const float*)d_in[9];
  const float* sh_gate = (const float*)d_in[10];
  const float* sh_up = (const float*)d_in[11];
  const float* sh_down = (const float*)d_in[12];

  float* out = (float*)d_out;
  float* resid = out + (size_t)T * H;

  char* p = (char*)d_ws;
  auto alloc = [&](size_t bytes) { char* r = p; p += (bytes + 255) & ~(size_t)255; return r; };

  float* qkv = (float*)alloc((size_t)T * QKVN * 4);
  float* h2 = (float*)alloc((size_t)T * H * 4);
  float* gb1 = (float*)alloc((size_t)T * H * 4);
  float* outp = (float*)alloc((size_t)T * H * 4);
  __hip_bfloat16* h1b = (__hip_bfloat16*)alloc((size_t)T * H * 2);
  __hip_bfloat16* aob = (__hip_bfloat16*)alloc((size_t)T * H * 2);
  __hip_bfloat16* h2b = (__hip_bfloat16*)alloc((size_t)T * H * 2);
  __hip_bfloat16* xgb = (__hip_bfloat16*)alloc((size_t)T * H * 2);
  __hip_bfloat16* gA = (__hip_bfloat16*)alloc((size_t)T * FF * 2);
  __hip_bfloat16* gB = (__hip_bfloat16*)alloc((size_t)T * FF * 2);
  __hip_bfloat16* gP = (__hip_bfloat16*)alloc((size_t)T * FF * 2);
  __hip_bfloat16* Qb = (__hip_bfloat16*)alloc((size_t)T * NH * DH * 2);
  __hip_bfloat16* Kb = (__hip_bfloat16*)alloc((size_t)T * NKV * DH * 2);
  __hip_bfloat16* VtG = (__hip_bfloat16*)alloc((size_t)NKV * DH * T * 2);
  __hip_bfloat16* wqkvT = (__hip_bfloat16*)alloc((size_t)H * QKVN * 2);
  __hip_bfloat16* woT = (__hip_bfloat16*)alloc((size_t)H * H * 2);
  __hip_bfloat16* shgT = (__hip_bfloat16*)alloc((size_t)H * FF * 2);
  __hip_bfloat16* shuT = (__hip_bfloat16*)alloc((size_t)H * FF * 2);
  __hip_bfloat16* shdT = (__hip_bfloat16*)alloc((size_t)H * FF * 2);
  __hip_bfloat16* wgT = (__hip_bfloat16*)alloc((size_t)NE * H * FF * 2);
  __hip_bfloat16* wuT = (__hip_bfloat16*)alloc((size_t)NE * H * FF * 2);
  __hip_bfloat16* wdT = (__hip_bfloat16*)alloc((size_t)NE * H * FF * 2);
  int* counts = (int*)alloc(2 * NE * 4);
  int* cnt2 = counts + NE;
  int* offs = (int*)alloc((NE + 1) * 4);
  int* idx = (int*)alloc(T * 4);
  int* perm = (int*)alloc(T * 4);
  int* pos = (int*)alloc(T * 4);
  float* gate = (float*)alloc(T * 4);

  // weight transpose+cast (once per launch)
  tcast<<<dim3(QKVN / 32, H / 32, 1), 256, 0, stream>>>(wqkv, wqkvT, H, QKVN, QKVN, H, 0, 0);
  tcast<<<dim3(H / 32, H / 32, 1), 256, 0, stream>>>(wo, woT, H, H, H, H, 0, 0);
  tcast<<<dim3(FF / 32, H / 32, 1), 256, 0, stream>>>(sh_gate, shgT, H, FF, FF, H, 0, 0);
  tcast<<<dim3(FF / 32, H / 32, 1), 256, 0, stream>>>(sh_up, shuT, H, FF, FF, H, 0, 0);
  tcast<<<dim3(H / 32, FF / 32, 1), 256, 0, stream>>>(sh_down, shdT, FF, H, H, FF, 0, 0);
  tcast<<<dim3(FF / 32, H / 32, NE), 256, 0, stream>>>(w_gate, wgT, H, FF, FF, H, (long long)H * FF, (long long)H * FF);
  tcast<<<dim3(FF / 32, H / 32, NE), 256, 0, stream>>>(w_up, wuT, H, FF, FF, H, (long long)H * FF, (long long)H * FF);
  tcast<<<dim3(H / 32, FF / 32, NE), 256, 0, stream>>>(w_down, wdT, FF, H, H, FF, (long long)FF * H, (long long)FF * H);

  // 1. h1b = bf16(rmsnorm(hidden) * ln1_w)
  rmsnorm1024<<<T, 256, 0, stream>>>(hidden, ln1_w, nullptr, h1b);
  // 2. qkv = h1 @ wqkv (fp32)
  gemm_bf16<<<dim3(QKVN / 128, T / 128, 1), 256, 0, stream>>>(h1b, wqkvT, qkv, T, QKVN, H, 0, nullptr, 0);
  // 3. RoPE + q/k rmsnorm
  rope_norm_kernel<<<T * (NH + NKV) / 4, 256, 0, stream>>>(qkv, positions);
  // 4a. pack Q (scaled), K to bf16
  pack_qk<<<T * (NH + NKV) * DH / 4 / 256, 256, 0, stream>>>(qkv, Qb, Kb);
  // 4b. V^T bf16: [NKV*DH][T]
  tcast<<<dim3(NKV * DH / 32, T / 32, 1), 256, 0, stream>>>(qkv + (NH + NKV) * DH, VtG, T, NKV * DH, QKVN, T, 0, 0);
  // 4c. attention
  attn_mfma<<<dim3(T / 64, NH), 256, 0, stream>>>(Qb, Kb, VtG, aob);
  // 5. gb1 = ao @ wo (fp32)
  gemm_bf16<<<dim3(H / 128, T / 128, 1), 256, 0, stream>>>(aob, woT, gb1, T, H, H, 0, nullptr, 0);
  // 6. resid = gb1 + hidden
  add_kernel<<<(T * H / 4 + 255) / 256, 256, 0, stream>>>(gb1, hidden, resid, T * H / 4);
  // 7. h2 (fp32) + h2b (bf16)
  rmsnorm1024<<<T, 256, 0, stream>>>(resid, ln2_w, h2, h2b);
  // 8-11. routing
  zero_counts_kernel<<<1, 64, 0, stream>>>(counts);
  router_kernel<<<T, 64, 0, stream>>>(h2, router_w, idx, gate, counts);
  scan_kernel<<<1, 64, 0, stream>>>(counts, offs);
  assign_kernel<<<T / 256, 256, 0, stream>>>(idx, offs, cnt2, perm, pos);
  // 12. gather
  gather_kernel<<<T, 256, 0, stream>>>(h2, gate, perm, xgb);
  // 13/14. grouped expert gate/up
  gemm_bf16<<<dim3(FF / 128, T / 128, NE), 256, 0, stream>>>(xgb, wgT, gA, T, FF, H, 1, offs, (long long)H * FF);
  gemm_bf16<<<dim3(FF / 128, T / 128, NE), 256, 0, stream>>>(xgb, wuT, gB, T, FF, H, 1, offs, (long long)H * FF);
  // 15. gP = silu(gA) * gB
  silumul_bf16<<<(T * FF / 4 + 255) / 256, 256, 0, stream>>>(gA, gB, gP, T * FF / 4);
  // 16. outp = gP @ w_down[e]
  gemm_bf16<<<dim3(H / 128, T / 128, NE), 256, 0, stream>>>(gP, wdT, outp, T, H, FF, 0, offs, (long long)FF * H);
  // 17-20. shared expert
  gemm_bf16<<<dim3(FF / 128, T / 128, 1), 256, 0, stream>>>(h2b, shgT, gA, T, FF, H, 1, nullptr, 0);
  gemm_bf16<<<dim3(FF / 128, T / 128, 1), 256, 0, stream>>>(h2b, shuT, gB, T, FF, H, 1, nullptr, 0);
  silumul_bf16<<<(T * FF / 4 + 255) / 256, 256, 0, stream>>>(gA, gB, gP, T * FF / 4);
  gemm_bf16<<<dim3(H / 128, T / 128, 1), 256, 0, stream>>>(gP, shdT, out, T, H, FF, 0, nullptr, 0);
  // 21. out += routed
  final_add_kernel<<<T, 256, 0, stream>>>(out, outp, pos);
}

// Round 4
// 526.231 us; speedup vs baseline: 3.1079x; 1.1638x over previous
//
#include <hip/hip_runtime.h>
#include <hip/hip_bf16.h>
#include <cmath>
#include <cstdint>

#define T 2048
#define H 1024
#define NH 16
#define NKV 4
#define DH 64
#define NE 8
#define FF 1024
#define QKVN ((NH + 2 * NKV) * DH) /* 1536 */
#define EPS 1e-5f
#define ATTN_SCALE 0.125f

typedef short bf16x8 __attribute__((ext_vector_type(8)));
typedef float floatx4 __attribute__((ext_vector_type(4)));

__device__ __forceinline__ void gload16(const void* g, void* l) {
  __builtin_amdgcn_global_load_lds((const __attribute__((address_space(1))) void*)g,
                                   (__attribute__((address_space(3))) void*)l, 16, 0, 0);
}

// ---------------- rmsnorm rows of 1024 -> bf16 ----------------
__global__ __launch_bounds__(256) void rmsnorm1024(const float* __restrict__ x,
                                                   const float* __restrict__ w,
                                                   __hip_bfloat16* __restrict__ yb) {
  int row = blockIdx.x;
  const float4* x4 = (const float4*)(x + (size_t)row * H);
  float4 v = x4[threadIdx.x];
  float s = v.x * v.x + v.y * v.y + v.z * v.z + v.w * v.w;
  #pragma unroll
  for (int o = 32; o; o >>= 1) s += __shfl_down(s, o, 64);
  __shared__ float red[4];
  if ((threadIdx.x & 63) == 0) red[threadIdx.x >> 6] = s;
  __syncthreads();
  s = red[0] + red[1] + red[2] + red[3];
  float inv = rsqrtf(s * (1.0f / (float)H) + EPS);
  float4 wv = ((const float4*)w)[threadIdx.x];
  __hip_bfloat16* yp = yb + (size_t)row * H + threadIdx.x * 4;
  yp[0] = __float2bfloat16(v.x * inv * wv.x);
  yp[1] = __float2bfloat16(v.y * inv * wv.y);
  yp[2] = __float2bfloat16(v.z * inv * wv.z);
  yp[3] = __float2bfloat16(v.w * inv * wv.w);
}

// -------- fused: resid = a+b; h2 = rmsnorm(resid)*w (fp32 + bf16) --------
__global__ __launch_bounds__(256) void fused_add_rms(const float* __restrict__ a,
                                                     const float* __restrict__ b,
                                                     float* __restrict__ resid,
                                                     const float* __restrict__ w,
                                                     float* __restrict__ yf,
                                                     __hip_bfloat16* __restrict__ yb) {
  int row = blockIdx.x;
  float4 av = ((const float4*)(a + (size_t)row * H))[threadIdx.x];
  float4 bv = ((const float4*)(b + (size_t)row * H))[threadIdx.x];
  float4 v = make_float4(av.x + bv.x, av.y + bv.y, av.z + bv.z, av.w + bv.w);
  ((float4*)(resid + (size_t)row * H))[threadIdx.x] = v;
  float s = v.x * v.x + v.y * v.y + v.z * v.z + v.w * v.w;
  #pragma unroll
  for (int o = 32; o; o >>= 1) s += __shfl_down(s, o, 64);
  __shared__ float red[4];
  if ((threadIdx.x & 63) == 0) red[threadIdx.x >> 6] = s;
  __syncthreads();
  s = red[0] + red[1] + red[2] + red[3];
  float inv = rsqrtf(s * (1.0f / (float)H) + EPS);
  float4 wv = ((const float4*)w)[threadIdx.x];
  float o0 = v.x * inv * wv.x, o1 = v.y * inv * wv.y, o2 = v.z * inv * wv.z, o3 = v.w * inv * wv.w;
  ((float4*)(yf + (size_t)row * H))[threadIdx.x] = make_float4(o0, o1, o2, o3);
  __hip_bfloat16* yp = yb + (size_t)row * H + threadIdx.x * 4;
  yp[0] = __float2bfloat16(o0);
  yp[1] = __float2bfloat16(o1);
  yp[2] = __float2bfloat16(o2);
  yp[3] = __float2bfloat16(o3);
}

// ------- fp32 [R][C] -> bf16 [C][R], 64c x 32r tile, 16B writes -------
__global__ __launch_bounds__(256) void tcast2(const float* __restrict__ src,
                                              __hip_bfloat16* __restrict__ dst, int R, int C,
                                              long long srcStride, long long dstStride,
                                              long long sBatch, long long dBatch) {
  src += (long long)blockIdx.z * sBatch;
  dst += (long long)blockIdx.z * dBatch;
  int c0 = blockIdx.x * 64, r0 = blockIdx.y * 32;
  __shared__ float tile[32][65];
  int tid = threadIdx.x;
  int lr = tid >> 4;
  int lc = (tid & 15) * 4;
  #pragma unroll
  for (int it = 0; it < 2; it++) {
    float4 v = *(const float4*)(src + (long long)(r0 + lr + it * 16) * srcStride + c0 + lc);
    tile[lr + it * 16][lc + 0] = v.x;
    tile[lr + it * 16][lc + 1] = v.y;
    tile[lr + it * 16][lc + 2] = v.z;
    tile[lr + it * 16][lc + 3] = v.w;
  }
  __syncthreads();
  int oc = tid >> 2;
  int rr = (tid & 3) * 8;
  short ov[8];
  #pragma unroll
  for (int i = 0; i < 8; i++) {
    __hip_bfloat16 b = __float2bfloat16(tile[rr + i][oc]);
    ov[i] = *(short*)&b;
  }
  *(bf16x8*)((short*)dst + (long long)(c0 + oc) * dstStride + r0 + rr) = *(bf16x8*)ov;
}

// ---------------- bf16 MFMA GEMM: C[M,N] = A[M,K] * Bt[N,K]^T ----------------
__global__ __launch_bounds__(256) void gemm_bf16(const __hip_bfloat16* __restrict__ A,
                                                 const __hip_bfloat16* __restrict__ Bt,
                                                 void* __restrict__ Cout, int M, int N, int K,
                                                 int out_bf16, const int* __restrict__ row_offs,
                                                 long long strideB) {
  int e = blockIdx.z;
  int rbeg = 0, rend = M;
  if (row_offs) { rbeg = row_offs[e]; rend = row_offs[e + 1]; }
  long long m0 = rbeg + (long long)blockIdx.y * 128;
  if (m0 >= rend) return;
  long long n0 = (long long)blockIdx.x * 128;
  const __hip_bfloat16* Bp = Bt + (long long)e * strideB;

  __shared__ unsigned short As[128 * 32];
  __shared__ unsigned short Bs[128 * 32];

  int tid = threadIdx.x;
  int lane = tid & 63, w = tid >> 6;
  int wr = (w >> 1) * 64, wc = (w & 1) * 64;
  int qd = lane >> 4, ln16 = lane & 15;

  floatx4 acc[4][4];
  floatx4 zero = {0.f, 0.f, 0.f, 0.f};
  #pragma unroll
  for (int i = 0; i < 4; i++)
    #pragma unroll
    for (int j = 0; j < 4; j++) acc[i][j] = zero;

  int fe = tid * 8;
  int row0 = tid >> 2;
  int ko0 = (tid & 3) << 3;

  for (int k0 = 0; k0 < K; k0 += 32) {
    long long ra0 = m0 + row0;       if (ra0 >= rend) ra0 = rend - 1;
    long long ra1 = m0 + row0 + 64;  if (ra1 >= rend) ra1 = rend - 1;
    gload16(A + ra0 * K + k0 + ko0, As + fe);
    gload16(A + ra1 * K + k0 + ko0, As + fe + 2048);
    gload16(Bp + (n0 + row0) * K + k0 + ko0, Bs + fe);
    gload16(Bp + (n0 + row0 + 64) * K + k0 + ko0, Bs + fe + 2048);
    __syncthreads();
    bf16x8 af[4], bfr[4];
    #pragma unroll
    for (int i = 0; i < 4; i++)
      af[i] = *(const bf16x8*)(As + (wr + i * 16 + ln16) * 32 + qd * 8);
    #pragma unroll
    for (int j = 0; j < 4; j++)
      bfr[j] = *(const bf16x8*)(Bs + (wc + j * 16 + ln16) * 32 + qd * 8);
    #pragma unroll
    for (int i = 0; i < 4; i++)
      #pragma unroll
      for (int j = 0; j < 4; j++)
        acc[i][j] = __builtin_amdgcn_mfma_f32_16x16x32_bf16(af[i], bfr[j], acc[i][j], 0, 0, 0);
    __syncthreads();
  }

  #pragma unroll
  for (int i = 0; i < 4; i++) {
    #pragma unroll
    for (int r = 0; r < 4; r++) {
      long long gm = m0 + wr + i * 16 + qd * 4 + r;
      if (gm < rend) {
        #pragma unroll
        for (int j = 0; j < 4; j++) {
          long long gn = n0 + wc + j * 16 + ln16;
          float v = acc[i][j][r];
          if (out_bf16)
            ((__hip_bfloat16*)Cout)[gm * N + gn] = __float2bfloat16(v);
          else
            ((float*)Cout)[gm * N + gn] = v;
        }
      }
    }
  }
}

// -------- RoPE + per-head rmsnorm; writes Qb (scaled) and Kb bf16 --------
__global__ __launch_bounds__(256) void rope_pack(const float* __restrict__ qkv,
                                                 const int* __restrict__ positions,
                                                 __hip_bfloat16* __restrict__ Qb,
                                                 __hip_bfloat16* __restrict__ Kb) {
  int b = blockIdx.x * 4 + (threadIdx.x >> 6);
  int t = b / (NH + NKV);
  int hh = b % (NH + NKV);
  const float* ptr = qkv + (long long)t * QKVN + hh * DH;
  int d = threadIdx.x & 63;
  float v = ptr[d];
  int fi = d & 31;
  float inv_freq = exp2f(-(float)fi * (18.93156857f / 32.0f));
  float ang = (float)positions[t] * inv_freq;
  float c = __cosf(ang), s = __sinf(ang);
  float other = __shfl_xor(v, 32, 64);
  float r = (d < 32) ? (v * c - other * s) : (v * c + other * s);
  float sq = r * r;
  #pragma unroll
  for (int off = 32; off; off >>= 1) sq += __shfl_xor(sq, off, 64);
  float o = r * rsqrtf(sq * (1.0f / (float)DH) + EPS);
  if (hh < NH)
    Qb[(size_t)t * (NH * DH) + hh * DH + d] = __float2bfloat16(o * ATTN_SCALE);
  else
    Kb[(size_t)t * (NKV * DH) + (hh - NH) * DH + d] = __float2bfloat16(o);
}

// ---------------- MFMA flash attention, XOR-swizzled LDS ----------------
__global__ __launch_bounds__(256) void attn_mfma(const __hip_bfloat16* __restrict__ Qb,
                                                 const __hip_bfloat16* __restrict__ Kb,
                                                 const __hip_bfloat16* __restrict__ VtG,
                                                 __hip_bfloat16* __restrict__ ao) {
  int h = blockIdx.y;
  int kvh = h >> 2;
  int nb = gridDim.x;
  int bx = blockIdx.x;
  int qi = (bx & 1) ? (nb - 1 - (bx >> 1)) : (bx >> 1);
  int q0 = qi * 64;

  __shared__ unsigned short Ks[64 * 64];
  __shared__ unsigned short Vs[64 * 64];
  __shared__ unsigned short Ps[4 * 16 * 64];

  int tid = threadIdx.x;
  int lane = tid & 63, w = tid >> 6;
  int qd = lane >> 4, ln16 = lane & 15;
  int l7 = ln16 & 7;
  unsigned short* Pw = Ps + w * 16 * 64;

  // staging coords (XOR swizzle of source column)
  int r0 = tid >> 3;
  int sc = ((tid & 7) ^ (r0 & 7)) * 8;

  int tq = q0 + w * 16 + ln16;
  const unsigned short* qp = (const unsigned short*)Qb + (size_t)tq * (NH * DH) + h * DH;
  bf16x8 aq[2];
  aq[0] = *(const bf16x8*)(qp + qd * 8);
  aq[1] = *(const bf16x8*)(qp + 32 + qd * 8);

  floatx4 O_[4];
  floatx4 zero = {0.f, 0.f, 0.f, 0.f};
  #pragma unroll
  for (int j = 0; j < 4; j++) O_[j] = zero;
  float m_[4] = {-1e30f, -1e30f, -1e30f, -1e30f};
  float l_[4] = {0.f, 0.f, 0.f, 0.f};
  int tq_base = q0 + w * 16 + qd * 4;

  for (int kb = 0; kb < q0 + 64; kb += 64) {
    gload16((const unsigned short*)Kb + (size_t)(kb + r0) * (NKV * DH) + kvh * DH + sc, Ks + tid * 8);
    gload16((const unsigned short*)Kb + (size_t)(kb + r0 + 32) * (NKV * DH) + kvh * DH + sc, Ks + tid * 8 + 2048);
    gload16((const unsigned short*)VtG + (size_t)(kvh * DH + r0) * T + kb + sc, Vs + tid * 8);
    gload16((const unsigned short*)VtG + (size_t)(kvh * DH + r0 + 32) * T + kb + sc, Vs + tid * 8 + 2048);
    __syncthreads();

    floatx4 S_[4];
    #pragma unroll
    for (int j = 0; j < 4; j++) S_[j] = zero;
    #pragma unroll
    for (int s = 0; s < 2; s++) {
      bf16x8 bk[4];
      #pragma unroll
      for (int j = 0; j < 4; j++)
        bk[j] = *(const bf16x8*)(Ks + (j * 16 + ln16) * 64 + (((s * 4 + qd) ^ l7) * 8));
      #pragma unroll
      for (int j = 0; j < 4; j++)
        S_[j] = __builtin_amdgcn_mfma_f32_16x16x32_bf16(aq[s], bk[j], S_[j], 0, 0, 0);
    }

    float mx[4] = {-1e30f, -1e30f, -1e30f, -1e30f};
    #pragma unroll
    for (int j = 0; j < 4; j++) {
      int tk = kb + j * 16 + ln16;
      #pragma unroll
      for (int r = 0; r < 4; r++) {
        float sv = (tk <= tq_base + r) ? S_[j][r] : -1e30f;
        S_[j][r] = sv;
        mx[r] = fmaxf(mx[r], sv);
      }
    }
    #pragma unroll
    for (int off = 8; off; off >>= 1)
      #pragma unroll
      for (int r = 0; r < 4; r++) mx[r] = fmaxf(mx[r], __shfl_xor(mx[r], off, 64));
    float al[4], psum[4] = {0.f, 0.f, 0.f, 0.f};
    #pragma unroll
    for (int r = 0; r < 4; r++) {
      float mn = fmaxf(m_[r], mx[r]);
      al[r] = __expf(m_[r] - mn);
      m_[r] = mn;
    }
    #pragma unroll
    for (int j = 0; j < 4; j++)
      #pragma unroll
      for (int r = 0; r < 4; r++) {
        float pv = __expf(S_[j][r] - m_[r]);
        S_[j][r] = pv;
        psum[r] += pv;
      }
    #pragma unroll
    for (int off = 8; off; off >>= 1)
      #pragma unroll
      for (int r = 0; r < 4; r++) psum[r] += __shfl_xor(psum[r], off, 64);
    #pragma unroll
    for (int r = 0; r < 4; r++) l_[r] = l_[r] * al[r] + psum[r];

    // P -> per-wave LDS (bf16, XOR swizzle)
    #pragma unroll
    for (int j = 0; j < 4; j++)
      #pragma unroll
      for (int r = 0; r < 4; r++) {
        int row = qd * 4 + r;
        int pc = (((j * 2 + (ln16 >> 3)) ^ (row & 7)) * 8) + l7;
        __hip_bfloat16 pb = __float2bfloat16(S_[j][r]);
        Pw[row * 64 + pc] = *(unsigned short*)&pb;
      }

    #pragma unroll
    for (int j = 0; j < 4; j++)
      #pragma unroll
      for (int r = 0; r < 4; r++) O_[j][r] *= al[r];
    #pragma unroll
    for (int s = 0; s < 2; s++) {
      bf16x8 ap = *(const bf16x8*)(Pw + ln16 * 64 + (((s * 4 + qd) ^ l7) * 8));
      bf16x8 bv[4];
      #pragma unroll
      for (int j = 0; j < 4; j++)
        bv[j] = *(const bf16x8*)(Vs + (j * 16 + ln16) * 64 + (((s * 4 + qd) ^ l7) * 8));
      #pragma unroll
      for (int j = 0; j < 4; j++)
        O_[j] = __builtin_amdgcn_mfma_f32_16x16x32_bf16(ap, bv[j], O_[j], 0, 0, 0);
    }
    __syncthreads();
  }

  float inv[4];
  #pragma unroll
  for (int r = 0; r < 4; r++) inv[r] = 1.0f / l_[r];
  #pragma unroll
  for (int j = 0; j < 4; j++)
    #pragma unroll
    for (int r = 0; r < 4; r++)
      ao[(size_t)(tq_base + r) * (NH * DH) + h * DH + j * 16 + ln16] =
          __float2bfloat16(O_[j][r] * inv[r]);
}

// ---------------- elementwise: y = silu(x[:, :F]) * x[:, F:2F] ----------------
__global__ void silumul2(const __hip_bfloat16* __restrict__ x2, __hip_bfloat16* __restrict__ y,
                         int n4) {
  int i = blockIdx.x * blockDim.x + threadIdx.x;
  if (i >= n4) return;
  int el = i * 4;
  int row = el >> 10;            // /FF
  int c = el & (FF - 1);
  const __hip_bfloat16* g = x2 + (size_t)row * (2 * FF) + c;
  #pragma unroll
  for (int k = 0; k < 4; k++) {
    float av = __bfloat162float(g[k]);
    float bv = __bfloat162float(g[FF + k]);
    y[el + k] = __float2bfloat16(av / (1.f + __expf(-av)) * bv);
  }
}

// ---------------- router (top-1 + sigmoid gate), fp32 ----------------
__global__ __launch_bounds__(64) void router_kernel(const float* __restrict__ h2,
                                                    const float* __restrict__ rw,
                                                    int* __restrict__ idx,
                                                    float* __restrict__ gate,
                                                    int* __restrict__ counts) {
  int t = blockIdx.x;
  int lane = threadIdx.x;
  float acc[NE] = {};
  for (int k = lane; k < H; k += 64) {
    float hv = h2[(long long)t * H + k];
    float4 r0 = *(const float4*)(rw + (long long)k * NE);
    float4 r1 = *(const float4*)(rw + (long long)k * NE + 4);
    acc[0] += hv * r0.x; acc[1] += hv * r0.y; acc[2] += hv * r0.z; acc[3] += hv * r0.w;
    acc[4] += hv * r1.x; acc[5] += hv * r1.y; acc[6] += hv * r1.z; acc[7] += hv * r1.w;
  }
  #pragma unroll
  for (int off = 32; off; off >>= 1)
    #pragma unroll
    for (int e2 = 0; e2 < NE; e2++) acc[e2] += __shfl_down(acc[e2], off, 64);
  if (lane == 0) {
    int best = 0;
    float bv = acc[0];
    #pragma unroll
    for (int e2 = 1; e2 < NE; e2++)
      if (acc[e2] > bv) { bv = acc[e2]; best = e2; }
    idx[t] = best;
    gate[t] = 1.f / (1.f + expf(-bv));
    atomicAdd(&counts[best], 1);
  }
}

__global__ void zero_counts_kernel(int* c) {
  if (threadIdx.x < 2 * NE) c[threadIdx.x] = 0;
}

__global__ void scan_kernel(const int* __restrict__ counts, int* __restrict__ offs) {
  if (threadIdx.x == 0) {
    int s = 0;
    for (int e2 = 0; e2 < NE; e2++) { offs[e2] = s; s += counts[e2]; }
    offs[NE] = s;
  }
}

__global__ void assign_kernel(const int* __restrict__ idx, const int* __restrict__ offs,
                              int* __restrict__ cnt2, int* __restrict__ perm,
                              int* __restrict__ pos) {
  int t = blockIdx.x * blockDim.x + threadIdx.x;
  if (t >= T) return;
  int e2 = idx[t];
  int p = offs[e2] + atomicAdd(&cnt2[e2], 1);
  pos[t] = p;
  perm[p] = t;
}

__global__ __launch_bounds__(256) void gather_kernel(const float* __restrict__ h2,
                                                     const float* __restrict__ gate,
                                                     const int* __restrict__ perm,
                                                     __hip_bfloat16* __restrict__ xg) {
  int p = blockIdx.x;
  int t = perm[p];
  float g = gate[t];
  float4 v = ((const float4*)(h2 + (long long)t * H))[threadIdx.x];
  __hip_bfloat16* yp = xg + (long long)p * H + threadIdx.x * 4;
  yp[0] = __float2bfloat16(v.x * g);
  yp[1] = __float2bfloat16(v.y * g);
  yp[2] = __float2bfloat16(v.z * g);
  yp[3] = __float2bfloat16(v.w * g);
}

__global__ __launch_bounds__(256) void final_add_kernel(float* __restrict__ out,
                                                        const float* __restrict__ outp,
                                                        const int* __restrict__ pos) {
  int t = blockIdx.x;
  int p = pos[t];
  const float4* src = (const float4*)(outp + (long long)p * H);
  float4* dst = (float4*)(out + (long long)t * H);
  float4 a = dst[threadIdx.x];
  float4 b = src[threadIdx.x];
  a.x += b.x; a.y += b.y; a.z += b.z; a.w += b.w;
  dst[threadIdx.x] = a;
}

// ---------------- launcher ----------------
extern "C" void kernel_launch(void* const* d_in, const int* in_sizes, int n_in,
                              void* d_out, int out_size, void* d_ws, size_t ws_size,
                              hipStream_t stream) {
  const int* positions = (const int*)d_in[0];
  const float* hidden = (const float*)d_in[1];
  const float* ln1_w = (const float*)d_in[2];
  const float* ln2_w = (const float*)d_in[3];
  const float* wqkv = (const float*)d_in[4];
  const float* wo = (const float*)d_in[5];
  const float* router_w = (const float*)d_in[6];
  const float* w_gate = (const float*)d_in[7];
  const float* w_up = (const float*)d_in[8];
  const float* w_down = (const float*)d_in[9];
  const float* sh_gate = (const float*)d_in[10];
  const float* sh_up = (const float*)d_in[11];
  const float* sh_down = (const float*)d_in[12];

  float* out = (float*)d_out;
  float* resid = out + (size_t)T * H;

  char* p = (char*)d_ws;
  auto alloc = [&](size_t bytes) { char* r = p; p += (bytes + 255) & ~(size_t)255; return r; };

  float* qkv = (float*)alloc((size_t)T * QKVN * 4);
  float* h2 = (float*)alloc((size_t)T * H * 4);
  float* gb1 = (float*)alloc((size_t)T * H * 4);
  float* outp = (float*)alloc((size_t)T * H * 4);
  __hip_bfloat16* h1b = (__hip_bfloat16*)alloc((size_t)T * H * 2);
  __hip_bfloat16* aob = (__hip_bfloat16*)alloc((size_t)T * H * 2);
  __hip_bfloat16* h2b = (__hip_bfloat16*)alloc((size_t)T * H * 2);
  __hip_bfloat16* xgb = (__hip_bfloat16*)alloc((size_t)T * H * 2);
  __hip_bfloat16* gA2 = (__hip_bfloat16*)alloc((size_t)T * 2 * FF * 2);
  __hip_bfloat16* gP = (__hip_bfloat16*)alloc((size_t)T * FF * 2);
  __hip_bfloat16* Qb = (__hip_bfloat16*)alloc((size_t)T * NH * DH * 2);
  __hip_bfloat16* Kb = (__hip_bfloat16*)alloc((size_t)T * NKV * DH * 2);
  __hip_bfloat16* VtG = (__hip_bfloat16*)alloc((size_t)NKV * DH * T * 2);
  __hip_bfloat16* wqkvT = (__hip_bfloat16*)alloc((size_t)H * QKVN * 2);
  __hip_bfloat16* woT = (__hip_bfloat16*)alloc((size_t)H * H * 2);
  __hip_bfloat16* shguT = (__hip_bfloat16*)alloc((size_t)2 * FF * H * 2);
  __hip_bfloat16* shdT = (__hip_bfloat16*)alloc((size_t)H * FF * 2);
  __hip_bfloat16* wguT = (__hip_bfloat16*)alloc((size_t)NE * 2 * FF * H * 2);
  __hip_bfloat16* wdT = (__hip_bfloat16*)alloc((size_t)NE * H * FF * 2);
  int* counts = (int*)alloc(2 * NE * 4);
  int* cnt2 = counts + NE;
  int* offs = (int*)alloc((NE + 1) * 4);
  int* idx = (int*)alloc(T * 4);
  int* perm = (int*)alloc(T * 4);
  int* pos = (int*)alloc(T * 4);
  float* gate = (float*)alloc(T * 4);

  // weight transpose+cast
  tcast2<<<dim3(QKVN / 64, H / 32, 1), 256, 0, stream>>>(wqkv, wqkvT, H, QKVN, QKVN, H, 0, 0);
  tcast2<<<dim3(H / 64, H / 32, 1), 256, 0, stream>>>(wo, woT, H, H, H, H, 0, 0);
  tcast2<<<dim3(FF / 64, H / 32, 1), 256, 0, stream>>>(sh_gate, shguT, H, FF, FF, H, 0, 0);
  tcast2<<<dim3(FF / 64, H / 32, 1), 256, 0, stream>>>(sh_up, shguT + (size_t)FF * H, H, FF, FF, H, 0, 0);
  tcast2<<<dim3(H / 64, FF / 32, 1), 256, 0, stream>>>(sh_down, shdT, FF, H, H, FF, 0, 0);
  tcast2<<<dim3(FF / 64, H / 32, NE), 256, 0, stream>>>(w_gate, wguT, H, FF, FF, H,
                                                        (long long)H * FF, (long long)2 * H * FF);
  tcast2<<<dim3(FF / 64, H / 32, NE), 256, 0, stream>>>(w_up, wguT + (size_t)FF * H, H, FF, FF, H,
                                                        (long long)H * FF, (long long)2 * H * FF);
  tcast2<<<dim3(H / 64, FF / 32, NE), 256, 0, stream>>>(w_down, wdT, FF, H, H, FF,
                                                        (long long)FF * H, (long long)H * FF);

  // 1. h1b = bf16(rmsnorm(hidden) * ln1_w)
  rmsnorm1024<<<T, 256, 0, stream>>>(hidden, ln1_w, h1b);
  // 2. qkv = h1 @ wqkv (fp32)
  gemm_bf16<<<dim3(QKVN / 128, T / 128, 1), 256, 0, stream>>>(h1b, wqkvT, qkv, T, QKVN, H, 0, nullptr, 0);
  // 3. RoPE + q/k rmsnorm -> Qb, Kb (bf16)
  rope_pack<<<T * (NH + NKV) / 4, 256, 0, stream>>>(qkv, positions, Qb, Kb);
  // 4a. V^T bf16 [NKV*DH][T]
  tcast2<<<dim3(NKV * DH / 64, T / 32, 1), 256, 0, stream>>>(qkv + (NH + NKV) * DH, VtG, T, NKV * DH, QKVN, T, 0, 0);
  // 4b. attention
  attn_mfma<<<dim3(T / 64, NH), 256, 0, stream>>>(Qb, Kb, VtG, aob);
  // 5. gb1 = ao @ wo (fp32)
  gemm_bf16<<<dim3(H / 128, T / 128, 1), 256, 0, stream>>>(aob, woT, gb1, T, H, H, 0, nullptr, 0);
  // 6+7. resid = gb1 + hidden; h2 = rmsnorm(resid)*ln2_w (fp32+bf16)
  fused_add_rms<<<T, 256, 0, stream>>>(gb1, hidden, resid, ln2_w, h2, h2b);
  // 8-11. routing
  zero_counts_kernel<<<1, 64, 0, stream>>>(counts);
  router_kernel<<<T, 64, 0, stream>>>(h2, router_w, idx, gate, counts);
  scan_kernel<<<1, 64, 0, stream>>>(counts, offs);
  assign_kernel<<<T / 256, 256, 0, stream>>>(idx, offs, cnt2, perm, pos);
  // 12. gather
  gather_kernel<<<T, 256, 0, stream>>>(h2, gate, perm, xgb);
  // 13. fused expert gate+up GEMM (N = 2*FF)
  gemm_bf16<<<dim3(2 * FF / 128, T / 128, NE), 256, 0, stream>>>(xgb, wguT, gA2, T, 2 * FF, H, 1,
                                                                 offs, (long long)2 * H * FF);
  // 14. gP = silu(gate) * up
  silumul2<<<(T * FF / 4 + 255) / 256, 256, 0, stream>>>(gA2, gP, T * FF / 4);
  // 15. outp = gP @ w_down[e] (fp32)
  gemm_bf16<<<dim3(H / 128, T / 128, NE), 256, 0, stream>>>(gP, wdT, outp, T, H, FF, 0, offs, (long long)FF * H);
  // 16. shared gate+up fused GEMM
  gemm_bf16<<<dim3(2 * FF / 128, T / 128, 1), 256, 0, stream>>>(h2b, shguT, gA2, T, 2 * FF, H, 1, nullptr, 0);
  silumul2<<<(T * FF / 4 + 255) / 256, 256, 0, stream>>>(gA2, gP, T * FF / 4);
  gemm_bf16<<<dim3(H / 128, T / 128, 1), 256, 0, stream>>>(gP, shdT, out, T, H, FF, 0, nullptr, 0);
  // 17. out += routed
  final_add_kernel<<<T, 256, 0, stream>>>(out, outp, pos);
}

// Round 5
// 441.787 us; speedup vs baseline: 3.7019x; 1.1911x over previous
//
#include <hip/hip_runtime.h>
#include <hip/hip_bf16.h>
#include <cmath>
#include <cstdint>

#define T 2048
#define H 1024
#define NH 16
#define NKV 4
#define DH 64
#define NE 8
#define FF 1024
#define QKVN ((NH + 2 * NKV) * DH) /* 1536 */
#define EPS 1e-5f
#define ATTN_SCALE 0.125f
#define LOG2E 1.44269504f

typedef short bf16x8 __attribute__((ext_vector_type(8)));
typedef float floatx4 __attribute__((ext_vector_type(4)));

__device__ __forceinline__ void gload16(const void* g, void* l) {
  __builtin_amdgcn_global_load_lds((const __attribute__((address_space(1))) void*)g,
                                   (__attribute__((address_space(3))) void*)l, 16, 0, 0);
}

// ---------------- rmsnorm rows of 1024 -> bf16 ----------------
__global__ __launch_bounds__(256) void rmsnorm1024(const float* __restrict__ x,
                                                   const float* __restrict__ w,
                                                   __hip_bfloat16* __restrict__ yb) {
  int row = blockIdx.x;
  const float4* x4 = (const float4*)(x + (size_t)row * H);
  float4 v = x4[threadIdx.x];
  float s = v.x * v.x + v.y * v.y + v.z * v.z + v.w * v.w;
  #pragma unroll
  for (int o = 32; o; o >>= 1) s += __shfl_down(s, o, 64);
  __shared__ float red[4];
  if ((threadIdx.x & 63) == 0) red[threadIdx.x >> 6] = s;
  __syncthreads();
  s = red[0] + red[1] + red[2] + red[3];
  float inv = rsqrtf(s * (1.0f / (float)H) + EPS);
  float4 wv = ((const float4*)w)[threadIdx.x];
  __hip_bfloat16* yp = yb + (size_t)row * H + threadIdx.x * 4;
  yp[0] = __float2bfloat16(v.x * inv * wv.x);
  yp[1] = __float2bfloat16(v.y * inv * wv.y);
  yp[2] = __float2bfloat16(v.z * inv * wv.z);
  yp[3] = __float2bfloat16(v.w * inv * wv.w);
}

// -------- fused: resid = a+b; h2 = rmsnorm(resid)*w (fp32 + bf16) --------
__global__ __launch_bounds__(256) void fused_add_rms(const float* __restrict__ a,
                                                     const float* __restrict__ b,
                                                     float* __restrict__ resid,
                                                     const float* __restrict__ w,
                                                     float* __restrict__ yf,
                                                     __hip_bfloat16* __restrict__ yb) {
  int row = blockIdx.x;
  float4 av = ((const float4*)(a + (size_t)row * H))[threadIdx.x];
  float4 bv = ((const float4*)(b + (size_t)row * H))[threadIdx.x];
  float4 v = make_float4(av.x + bv.x, av.y + bv.y, av.z + bv.z, av.w + bv.w);
  ((float4*)(resid + (size_t)row * H))[threadIdx.x] = v;
  float s = v.x * v.x + v.y * v.y + v.z * v.z + v.w * v.w;
  #pragma unroll
  for (int o = 32; o; o >>= 1) s += __shfl_down(s, o, 64);
  __shared__ float red[4];
  if ((threadIdx.x & 63) == 0) red[threadIdx.x >> 6] = s;
  __syncthreads();
  s = red[0] + red[1] + red[2] + red[3];
  float inv = rsqrtf(s * (1.0f / (float)H) + EPS);
  float4 wv = ((const float4*)w)[threadIdx.x];
  float o0 = v.x * inv * wv.x, o1 = v.y * inv * wv.y, o2 = v.z * inv * wv.z, o3 = v.w * inv * wv.w;
  ((float4*)(yf + (size_t)row * H))[threadIdx.x] = make_float4(o0, o1, o2, o3);
  __hip_bfloat16* yp = yb + (size_t)row * H + threadIdx.x * 4;
  yp[0] = __float2bfloat16(o0);
  yp[1] = __float2bfloat16(o1);
  yp[2] = __float2bfloat16(o2);
  yp[3] = __float2bfloat16(o3);
}

// ------- fp32 [R][C] -> bf16 [C][R], 64c x 32r tile, 16B writes -------
__global__ __launch_bounds__(256) void tcast2(const float* __restrict__ src,
                                              __hip_bfloat16* __restrict__ dst, int R, int C,
                                              long long srcStride, long long dstStride,
                                              long long sBatch, long long dBatch) {
  src += (long long)blockIdx.z * sBatch;
  dst += (long long)blockIdx.z * dBatch;
  int c0 = blockIdx.x * 64, r0 = blockIdx.y * 32;
  __shared__ float tile[32][65];
  int tid = threadIdx.x;
  int lr = tid >> 4;
  int lc = (tid & 15) * 4;
  #pragma unroll
  for (int it = 0; it < 2; it++) {
    float4 v = *(const float4*)(src + (long long)(r0 + lr + it * 16) * srcStride + c0 + lc);
    tile[lr + it * 16][lc + 0] = v.x;
    tile[lr + it * 16][lc + 1] = v.y;
    tile[lr + it * 16][lc + 2] = v.z;
    tile[lr + it * 16][lc + 3] = v.w;
  }
  __syncthreads();
  int oc = tid >> 2;
  int rr = (tid & 3) * 8;
  short ov[8];
  #pragma unroll
  for (int i = 0; i < 8; i++) {
    __hip_bfloat16 b = __float2bfloat16(tile[rr + i][oc]);
    ov[i] = *(short*)&b;
  }
  *(bf16x8*)((short*)dst + (long long)(c0 + oc) * dstStride + r0 + rr) = *(bf16x8*)ov;
}

// ---------------- bf16 MFMA GEMM, 64x64 tile, BK=64, XOR-swizzled LDS ----------------
// C[M,N] = A[M,K] * Bt[N,K]^T ; 4 waves in 2x2, each wave 32x32 (2x2 MFMA frags).
__global__ __launch_bounds__(256) void gemm_bf16(const __hip_bfloat16* __restrict__ A,
                                                 const __hip_bfloat16* __restrict__ Bt,
                                                 void* __restrict__ Cout, int M, int N, int K,
                                                 int out_bf16, const int* __restrict__ row_offs,
                                                 long long strideB) {
  int e = blockIdx.z;
  int rbeg = 0, rend = M;
  if (row_offs) { rbeg = row_offs[e]; rend = row_offs[e + 1]; }
  long long m0 = rbeg + (long long)blockIdx.y * 64;
  if (m0 >= rend) return;
  long long n0 = (long long)blockIdx.x * 64;
  const __hip_bfloat16* Bp = Bt + (long long)e * strideB;

  __shared__ unsigned short As[64 * 64];
  __shared__ unsigned short Bs[64 * 64];

  int tid = threadIdx.x;
  int lane = tid & 63, w = tid >> 6;
  int wr = (w >> 1) * 32, wc = (w & 1) * 32;
  int qd = lane >> 4, ln16 = lane & 15;
  int l7 = ln16 & 7;

  floatx4 acc[2][2];
  floatx4 zero = {0.f, 0.f, 0.f, 0.f};
  #pragma unroll
  for (int i = 0; i < 2; i++)
    #pragma unroll
    for (int j = 0; j < 2; j++) acc[i][j] = zero;

  // staging: chunk = tid + it*256; row = chunk>>3, phys col8 = chunk&7,
  // source logical col8 = phys ^ (row&7)
  int row_s[2], kc_s[2];
  #pragma unroll
  for (int it = 0; it < 2; it++) {
    int chunk = tid + it * 256;
    row_s[it] = chunk >> 3;
    kc_s[it] = ((chunk & 7) ^ (row_s[it] & 7)) * 8;
  }

  for (int k0 = 0; k0 < K; k0 += 64) {
    #pragma unroll
    for (int it = 0; it < 2; it++) {
      long long ra = m0 + row_s[it];
      if (ra >= rend) ra = rend - 1;
      gload16(A + ra * K + k0 + kc_s[it], As + tid * 8 + it * 2048);
      gload16(Bp + (n0 + row_s[it]) * K + k0 + kc_s[it], Bs + tid * 8 + it * 2048);
    }
    __syncthreads();
    #pragma unroll
    for (int s = 0; s < 2; s++) {
      bf16x8 af[2], bfr[2];
      #pragma unroll
      for (int i = 0; i < 2; i++) {
        int row = wr + i * 16 + ln16;
        af[i] = *(const bf16x8*)(As + row * 64 + (((s * 4 + qd) ^ l7) * 8));
      }
      #pragma unroll
      for (int j = 0; j < 2; j++) {
        int row = wc + j * 16 + ln16;
        bfr[j] = *(const bf16x8*)(Bs + row * 64 + (((s * 4 + qd) ^ l7) * 8));
      }
      #pragma unroll
      for (int i = 0; i < 2; i++)
        #pragma unroll
        for (int j = 0; j < 2; j++)
          acc[i][j] = __builtin_amdgcn_mfma_f32_16x16x32_bf16(af[i], bfr[j], acc[i][j], 0, 0, 0);
    }
    __syncthreads();
  }

  #pragma unroll
  for (int i = 0; i < 2; i++) {
    #pragma unroll
    for (int r = 0; r < 4; r++) {
      long long gm = m0 + wr + i * 16 + qd * 4 + r;
      if (gm < rend) {
        #pragma unroll
        for (int j = 0; j < 2; j++) {
          long long gn = n0 + wc + j * 16 + ln16;
          float v = acc[i][j][r];
          if (out_bf16)
            ((__hip_bfloat16*)Cout)[gm * N + gn] = __float2bfloat16(v);
          else
            ((float*)Cout)[gm * N + gn] = v;
        }
      }
    }
  }
}

// -------- RoPE + per-head rmsnorm; Qb scaled by SCALE*log2e, Kb plain --------
__global__ __launch_bounds__(256) void rope_pack(const float* __restrict__ qkv,
                                                 const int* __restrict__ positions,
                                                 __hip_bfloat16* __restrict__ Qb,
                                                 __hip_bfloat16* __restrict__ Kb) {
  int b = blockIdx.x * 4 + (threadIdx.x >> 6);
  int t = b / (NH + NKV);
  int hh = b % (NH + NKV);
  const float* ptr = qkv + (long long)t * QKVN + hh * DH;
  int d = threadIdx.x & 63;
  float v = ptr[d];
  int fi = d & 31;
  float inv_freq = exp2f(-(float)fi * (18.93156857f / 32.0f));
  float ang = (float)positions[t] * inv_freq;
  float c = __cosf(ang), s = __sinf(ang);
  float other = __shfl_xor(v, 32, 64);
  float r = (d < 32) ? (v * c - other * s) : (v * c + other * s);
  float sq = r * r;
  #pragma unroll
  for (int off = 32; off; off >>= 1) sq += __shfl_xor(sq, off, 64);
  float o = r * rsqrtf(sq * (1.0f / (float)DH) + EPS);
  if (hh < NH)
    Qb[(size_t)t * (NH * DH) + hh * DH + d] = __float2bfloat16(o * (ATTN_SCALE * LOG2E));
  else
    Kb[(size_t)t * (NKV * DH) + (hh - NH) * DH + d] = __float2bfloat16(o);
}

// ---------------- MFMA flash attention, XOR-swizzled LDS, base-2 softmax ----------------
__global__ __launch_bounds__(256) void attn_mfma(const __hip_bfloat16* __restrict__ Qb,
                                                 const __hip_bfloat16* __restrict__ Kb,
                                                 const __hip_bfloat16* __restrict__ VtG,
                                                 __hip_bfloat16* __restrict__ ao) {
  int h = blockIdx.y;
  int kvh = h >> 2;
  int nb = gridDim.x;
  int bx = blockIdx.x;
  int qi = (bx & 1) ? (nb - 1 - (bx >> 1)) : (bx >> 1);
  int q0 = qi * 64;

  __shared__ unsigned short Ks[64 * 64];
  __shared__ unsigned short Vs[64 * 64];
  __shared__ unsigned short Ps[4 * 16 * 64];

  int tid = threadIdx.x;
  int lane = tid & 63, w = tid >> 6;
  int qd = lane >> 4, ln16 = lane & 15;
  int l7 = ln16 & 7;
  unsigned short* Pw = Ps + w * 16 * 64;

  int r0 = tid >> 3;
  int sc = ((tid & 7) ^ (r0 & 7)) * 8;

  int tq = q0 + w * 16 + ln16;
  const unsigned short* qp = (const unsigned short*)Qb + (size_t)tq * (NH * DH) + h * DH;
  bf16x8 aq[2];
  aq[0] = *(const bf16x8*)(qp + qd * 8);
  aq[1] = *(const bf16x8*)(qp + 32 + qd * 8);

  floatx4 O_[4];
  floatx4 zero = {0.f, 0.f, 0.f, 0.f};
  #pragma unroll
  for (int j = 0; j < 4; j++) O_[j] = zero;
  float m_[4] = {-1e30f, -1e30f, -1e30f, -1e30f};
  float l_[4] = {0.f, 0.f, 0.f, 0.f};
  int tq_base = q0 + w * 16 + qd * 4;
  int wave_min_row = q0 + w * 16;

  for (int kb = 0; kb < q0 + 64; kb += 64) {
    gload16((const unsigned short*)Kb + (size_t)(kb + r0) * (NKV * DH) + kvh * DH + sc, Ks + tid * 8);
    gload16((const unsigned short*)Kb + (size_t)(kb + r0 + 32) * (NKV * DH) + kvh * DH + sc, Ks + tid * 8 + 2048);
    gload16((const unsigned short*)VtG + (size_t)(kvh * DH + r0) * T + kb + sc, Vs + tid * 8);
    gload16((const unsigned short*)VtG + (size_t)(kvh * DH + r0 + 32) * T + kb + sc, Vs + tid * 8 + 2048);
    __syncthreads();

    floatx4 S_[4];
    #pragma unroll
    for (int j = 0; j < 4; j++) S_[j] = zero;
    #pragma unroll
    for (int s = 0; s < 2; s++) {
      bf16x8 bk[4];
      #pragma unroll
      for (int j = 0; j < 4; j++)
        bk[j] = *(const bf16x8*)(Ks + (j * 16 + ln16) * 64 + (((s * 4 + qd) ^ l7) * 8));
      #pragma unroll
      for (int j = 0; j < 4; j++)
        S_[j] = __builtin_amdgcn_mfma_f32_16x16x32_bf16(aq[s], bk[j], S_[j], 0, 0, 0);
    }

    float mx[4] = {-1e30f, -1e30f, -1e30f, -1e30f};
    if (kb + 63 > wave_min_row) {  // diagonal tile: apply causal mask
      #pragma unroll
      for (int j = 0; j < 4; j++) {
        int tk = kb + j * 16 + ln16;
        #pragma unroll
        for (int r = 0; r < 4; r++) {
          float sv = (tk <= tq_base + r) ? S_[j][r] : -1e30f;
          S_[j][r] = sv;
          mx[r] = fmaxf(mx[r], sv);
        }
      }
    } else {
      #pragma unroll
      for (int j = 0; j < 4; j++)
        #pragma unroll
        for (int r = 0; r < 4; r++) mx[r] = fmaxf(mx[r], S_[j][r]);
    }
    #pragma unroll
    for (int off = 8; off; off >>= 1)
      #pragma unroll
      for (int r = 0; r < 4; r++) mx[r] = fmaxf(mx[r], __shfl_xor(mx[r], off, 64));
    float al[4], psum[4] = {0.f, 0.f, 0.f, 0.f};
    #pragma unroll
    for (int r = 0; r < 4; r++) {
      float mn = fmaxf(m_[r], mx[r]);
      al[r] = exp2f(m_[r] - mn);
      m_[r] = mn;
    }
    #pragma unroll
    for (int j = 0; j < 4; j++)
      #pragma unroll
      for (int r = 0; r < 4; r++) {
        float pv = exp2f(S_[j][r] - m_[r]);
        S_[j][r] = pv;
        psum[r] += pv;
      }
    #pragma unroll
    for (int off = 8; off; off >>= 1)
      #pragma unroll
      for (int r = 0; r < 4; r++) psum[r] += __shfl_xor(psum[r], off, 64);
    #pragma unroll
    for (int r = 0; r < 4; r++) l_[r] = l_[r] * al[r] + psum[r];

    #pragma unroll
    for (int j = 0; j < 4; j++)
      #pragma unroll
      for (int r = 0; r < 4; r++) {
        int row = qd * 4 + r;
        int pc = (((j * 2 + (ln16 >> 3)) ^ (row & 7)) * 8) + l7;
        __hip_bfloat16 pb = __float2bfloat16(S_[j][r]);
        Pw[row * 64 + pc] = *(unsigned short*)&pb;
      }

    #pragma unroll
    for (int j = 0; j < 4; j++)
      #pragma unroll
      for (int r = 0; r < 4; r++) O_[j][r] *= al[r];
    #pragma unroll
    for (int s = 0; s < 2; s++) {
      bf16x8 ap = *(const bf16x8*)(Pw + ln16 * 64 + (((s * 4 + qd) ^ l7) * 8));
      bf16x8 bv[4];
      #pragma unroll
      for (int j = 0; j < 4; j++)
        bv[j] = *(const bf16x8*)(Vs + (j * 16 + ln16) * 64 + (((s * 4 + qd) ^ l7) * 8));
      #pragma unroll
      for (int j = 0; j < 4; j++)
        O_[j] = __builtin_amdgcn_mfma_f32_16x16x32_bf16(ap, bv[j], O_[j], 0, 0, 0);
    }
    __syncthreads();
  }

  float inv[4];
  #pragma unroll
  for (int r = 0; r < 4; r++) inv[r] = 1.0f / l_[r];
  #pragma unroll
  for (int j = 0; j < 4; j++)
    #pragma unroll
    for (int r = 0; r < 4; r++)
      ao[(size_t)(tq_base + r) * (NH * DH) + h * DH + j * 16 + ln16] =
          __float2bfloat16(O_[j][r] * inv[r]);
}

// ---------------- elementwise: y = silu(x[:, :F]) * x[:, F:2F] ----------------
__global__ void silumul2(const __hip_bfloat16* __restrict__ x2, __hip_bfloat16* __restrict__ y,
                         int n4) {
  int i = blockIdx.x * blockDim.x + threadIdx.x;
  if (i >= n4) return;
  int el = i * 4;
  int row = el >> 10;
  int c = el & (FF - 1);
  const __hip_bfloat16* g = x2 + (size_t)row * (2 * FF) + c;
  #pragma unroll
  for (int k = 0; k < 4; k++) {
    float av = __bfloat162float(g[k]);
    float bv = __bfloat162float(g[FF + k]);
    y[el + k] = __float2bfloat16(av / (1.f + __expf(-av)) * bv);
  }
}

// ---------------- router (top-1 + sigmoid gate), fp32 ----------------
__global__ __launch_bounds__(64) void router_kernel(const float* __restrict__ h2,
                                                    const float* __restrict__ rw,
                                                    int* __restrict__ idx,
                                                    float* __restrict__ gate,
                                                    int* __restrict__ counts) {
  int t = blockIdx.x;
  int lane = threadIdx.x;
  float acc[NE] = {};
  for (int k = lane; k < H; k += 64) {
    float hv = h2[(long long)t * H + k];
    float4 r0 = *(const float4*)(rw + (long long)k * NE);
    float4 r1 = *(const float4*)(rw + (long long)k * NE + 4);
    acc[0] += hv * r0.x; acc[1] += hv * r0.y; acc[2] += hv * r0.z; acc[3] += hv * r0.w;
    acc[4] += hv * r1.x; acc[5] += hv * r1.y; acc[6] += hv * r1.z; acc[7] += hv * r1.w;
  }
  #pragma unroll
  for (int off = 32; off; off >>= 1)
    #pragma unroll
    for (int e2 = 0; e2 < NE; e2++) acc[e2] += __shfl_down(acc[e2], off, 64);
  if (lane == 0) {
    int best = 0;
    float bv = acc[0];
    #pragma unroll
    for (int e2 = 1; e2 < NE; e2++)
      if (acc[e2] > bv) { bv = acc[e2]; best = e2; }
    idx[t] = best;
    gate[t] = 1.f / (1.f + expf(-bv));
    atomicAdd(&counts[best], 1);
  }
}

__global__ void zero_counts_kernel(int* c) {
  if (threadIdx.x < 2 * NE) c[threadIdx.x] = 0;
}

__global__ void scan_kernel(const int* __restrict__ counts, int* __restrict__ offs) {
  if (threadIdx.x == 0) {
    int s = 0;
    for (int e2 = 0; e2 < NE; e2++) { offs[e2] = s; s += counts[e2]; }
    offs[NE] = s;
  }
}

__global__ void assign_kernel(const int* __restrict__ idx, const int* __restrict__ offs,
                              int* __restrict__ cnt2, int* __restrict__ perm,
                              int* __restrict__ pos) {
  int t = blockIdx.x * blockDim.x + threadIdx.x;
  if (t >= T) return;
  int e2 = idx[t];
  int p = offs[e2] + atomicAdd(&cnt2[e2], 1);
  pos[t] = p;
  perm[p] = t;
}

__global__ __launch_bounds__(256) void gather_kernel(const float* __restrict__ h2,
                                                     const float* __restrict__ gate,
                                                     const int* __restrict__ perm,
                                                     __hip_bfloat16* __restrict__ xg) {
  int p = blockIdx.x;
  int t = perm[p];
  float g = gate[t];
  float4 v = ((const float4*)(h2 + (long long)t * H))[threadIdx.x];
  __hip_bfloat16* yp = xg + (long long)p * H + threadIdx.x * 4;
  yp[0] = __float2bfloat16(v.x * g);
  yp[1] = __float2bfloat16(v.y * g);
  yp[2] = __float2bfloat16(v.z * g);
  yp[3] = __float2bfloat16(v.w * g);
}

__global__ __launch_bounds__(256) void final_add_kernel(float* __restrict__ out,
                                                        const float* __restrict__ outp,
                                                        const int* __restrict__ pos) {
  int t = blockIdx.x;
  int p = pos[t];
  const float4* src = (const float4*)(outp + (long long)p * H);
  float4* dst = (float4*)(out + (long long)t * H);
  float4 a = dst[threadIdx.x];
  float4 b = src[threadIdx.x];
  a.x += b.x; a.y += b.y; a.z += b.z; a.w += b.w;
  dst[threadIdx.x] = a;
}

// ---------------- launcher ----------------
extern "C" void kernel_launch(void* const* d_in, const int* in_sizes, int n_in,
                              void* d_out, int out_size, void* d_ws, size_t ws_size,
                              hipStream_t stream) {
  const int* positions = (const int*)d_in[0];
  const float* hidden = (const float*)d_in[1];
  const float* ln1_w = (const float*)d_in[2];
  const float* ln2_w = (const float*)d_in[3];
  const float* wqkv = (const float*)d_in[4];
  const float* wo = (const float*)d_in[5];
  const float* router_w = (const float*)d_in[6];
  const float* w_gate = (const float*)d_in[7];
  const float* w_up = (const float*)d_in[8];
  const float* w_down = (const float*)d_in[9];
  const float* sh_gate = (const float*)d_in[10];
  const float* sh_up = (const float*)d_in[11];
  const float* sh_down = (const float*)d_in[12];

  float* out = (float*)d_out;
  float* resid = out + (size_t)T * H;

  char* p = (char*)d_ws;
  auto alloc = [&](size_t bytes) { char* r = p; p += (bytes + 255) & ~(size_t)255; return r; };

  float* qkv = (float*)alloc((size_t)T * QKVN * 4);
  float* h2 = (float*)alloc((size_t)T * H * 4);
  float* gb1 = (float*)alloc((size_t)T * H * 4);
  float* outp = (float*)alloc((size_t)T * H * 4);
  __hip_bfloat16* h1b = (__hip_bfloat16*)alloc((size_t)T * H * 2);
  __hip_bfloat16* aob = (__hip_bfloat16*)alloc((size_t)T * H * 2);
  __hip_bfloat16* h2b = (__hip_bfloat16*)alloc((size_t)T * H * 2);
  __hip_bfloat16* xgb = (__hip_bfloat16*)alloc((size_t)T * H * 2);
  __hip_bfloat16* gA2 = (__hip_bfloat16*)alloc((size_t)T * 2 * FF * 2);
  __hip_bfloat16* gP = (__hip_bfloat16*)alloc((size_t)T * FF * 2);
  __hip_bfloat16* Qb = (__hip_bfloat16*)alloc((size_t)T * NH * DH * 2);
  __hip_bfloat16* Kb = (__hip_bfloat16*)alloc((size_t)T * NKV * DH * 2);
  __hip_bfloat16* VtG = (__hip_bfloat16*)alloc((size_t)NKV * DH * T * 2);
  __hip_bfloat16* wqkvT = (__hip_bfloat16*)alloc((size_t)H * QKVN * 2);
  __hip_bfloat16* woT = (__hip_bfloat16*)alloc((size_t)H * H * 2);
  __hip_bfloat16* shguT = (__hip_bfloat16*)alloc((size_t)2 * FF * H * 2);
  __hip_bfloat16* shdT = (__hip_bfloat16*)alloc((size_t)H * FF * 2);
  __hip_bfloat16* wguT = (__hip_bfloat16*)alloc((size_t)NE * 2 * FF * H * 2);
  __hip_bfloat16* wdT = (__hip_bfloat16*)alloc((size_t)NE * H * FF * 2);
  int* counts = (int*)alloc(2 * NE * 4);
  int* cnt2 = counts + NE;
  int* offs = (int*)alloc((NE + 1) * 4);
  int* idx = (int*)alloc(T * 4);
  int* perm = (int*)alloc(T * 4);
  int* pos = (int*)alloc(T * 4);
  float* gate = (float*)alloc(T * 4);

  // weight transpose+cast
  tcast2<<<dim3(QKVN / 64, H / 32, 1), 256, 0, stream>>>(wqkv, wqkvT, H, QKVN, QKVN, H, 0, 0);
  tcast2<<<dim3(H / 64, H / 32, 1), 256, 0, stream>>>(wo, woT, H, H, H, H, 0, 0);
  tcast2<<<dim3(FF / 64, H / 32, 1), 256, 0, stream>>>(sh_gate, shguT, H, FF, FF, H, 0, 0);
  tcast2<<<dim3(FF / 64, H / 32, 1), 256, 0, stream>>>(sh_up, shguT + (size_t)FF * H, H, FF, FF, H, 0, 0);
  tcast2<<<dim3(H / 64, FF / 32, 1), 256, 0, stream>>>(sh_down, shdT, FF, H, H, FF, 0, 0);
  tcast2<<<dim3(FF / 64, H / 32, NE), 256, 0, stream>>>(w_gate, wguT, H, FF, FF, H,
                                                        (long long)H * FF, (long long)2 * H * FF);
  tcast2<<<dim3(FF / 64, H / 32, NE), 256, 0, stream>>>(w_up, wguT + (size_t)FF * H, H, FF, FF, H,
                                                        (long long)H * FF, (long long)2 * H * FF);
  tcast2<<<dim3(H / 64, FF / 32, NE), 256, 0, stream>>>(w_down, wdT, FF, H, H, FF,
                                                        (long long)FF * H, (long long)H * FF);

  // 1. h1b = bf16(rmsnorm(hidden) * ln1_w)
  rmsnorm1024<<<T, 256, 0, stream>>>(hidden, ln1_w, h1b);
  // 2. qkv = h1 @ wqkv (fp32)
  gemm_bf16<<<dim3(QKVN / 64, T / 64, 1), 256, 0, stream>>>(h1b, wqkvT, qkv, T, QKVN, H, 0, nullptr, 0);
  // 3. RoPE + q/k rmsnorm -> Qb (pre-scaled), Kb
  rope_pack<<<T * (NH + NKV) / 4, 256, 0, stream>>>(qkv, positions, Qb, Kb);
  // 4a. V^T bf16 [NKV*DH][T]
  tcast2<<<dim3(NKV * DH / 64, T / 32, 1), 256, 0, stream>>>(qkv + (NH + NKV) * DH, VtG, T, NKV * DH, QKVN, T, 0, 0);
  // 4b. attention
  attn_mfma<<<dim3(T / 64, NH), 256, 0, stream>>>(Qb, Kb, VtG, aob);
  // 5. gb1 = ao @ wo (fp32)
  gemm_bf16<<<dim3(H / 64, T / 64, 1), 256, 0, stream>>>(aob, woT, gb1, T, H, H, 0, nullptr, 0);
  // 6+7. resid = gb1 + hidden; h2 = rmsnorm(resid)*ln2_w
  fused_add_rms<<<T, 256, 0, stream>>>(gb1, hidden, resid, ln2_w, h2, h2b);
  // 8-11. routing
  zero_counts_kernel<<<1, 64, 0, stream>>>(counts);
  router_kernel<<<T, 64, 0, stream>>>(h2, router_w, idx, gate, counts);
  scan_kernel<<<1, 64, 0, stream>>>(counts, offs);
  assign_kernel<<<T / 256, 256, 0, stream>>>(idx, offs, cnt2, perm, pos);
  // 12. gather
  gather_kernel<<<T, 256, 0, stream>>>(h2, gate, perm, xgb);
  // 13. fused expert gate+up GEMM (N = 2*FF)
  gemm_bf16<<<dim3(2 * FF / 64, T / 64, NE), 256, 0, stream>>>(xgb, wguT, gA2, T, 2 * FF, H, 1,
                                                               offs, (long long)2 * H * FF);
  // 14. gP = silu(gate) * up
  silumul2<<<(T * FF / 4 + 255) / 256, 256, 0, stream>>>(gA2, gP, T * FF / 4);
  // 15. outp = gP @ w_down[e] (fp32)
  gemm_bf16<<<dim3(H / 64, T / 64, NE), 256, 0, stream>>>(gP, wdT, outp, T, H, FF, 0, offs, (long long)FF * H);
  // 16. shared gate+up fused GEMM
  gemm_bf16<<<dim3(2 * FF / 64, T / 64, 1), 256, 0, stream>>>(h2b, shguT, gA2, T, 2 * FF, H, 1, nullptr, 0);
  silumul2<<<(T * FF / 4 + 255) / 256, 256, 0, stream>>>(gA2, gP, T * FF / 4);
  gemm_bf16<<<dim3(H / 64, T / 64, 1), 256, 0, stream>>>(gP, shdT, out, T, H, FF, 0, nullptr, 0);
  // 17. out += routed
  final_add_kernel<<<T, 256, 0, stream>>>(out, outp, pos);
}

// Round 6
// 410.338 us; speedup vs baseline: 3.9857x; 1.0766x over previous
//
#include <hip/hip_runtime.h>
#include <hip/hip_bf16.h>
#include <cmath>
#include <cstdint>

#define T 2048
#define H 1024
#define NH 16
#define NKV 4
#define DH 64
#define NE 8
#define FF 1024
#define QKVN ((NH + 2 * NKV) * DH) /* 1536 */
#define EPS 1e-5f
#define ATTN_SCALE 0.125f
#define LOG2E 1.44269504f
#define MBOUND 12.0f  /* > 64*0.125*log2e = 11.54; scores can't exceed it (rms-normed q,k) */

typedef short bf16x8 __attribute__((ext_vector_type(8)));
typedef float floatx4 __attribute__((ext_vector_type(4)));

__device__ __forceinline__ void gload16(const void* g, void* l) {
  __builtin_amdgcn_global_load_lds((const __attribute__((address_space(1))) void*)g,
                                   (__attribute__((address_space(3))) void*)l, 16, 0, 0);
}

// ---------------- rmsnorm rows of 1024 -> bf16 ----------------
__global__ __launch_bounds__(256) void rmsnorm1024(const float* __restrict__ x,
                                                   const float* __restrict__ w,
                                                   __hip_bfloat16* __restrict__ yb) {
  int row = blockIdx.x;
  const float4* x4 = (const float4*)(x + (size_t)row * H);
  float4 v = x4[threadIdx.x];
  float s = v.x * v.x + v.y * v.y + v.z * v.z + v.w * v.w;
  #pragma unroll
  for (int o = 32; o; o >>= 1) s += __shfl_down(s, o, 64);
  __shared__ float red[4];
  if ((threadIdx.x & 63) == 0) red[threadIdx.x >> 6] = s;
  __syncthreads();
  s = red[0] + red[1] + red[2] + red[3];
  float inv = rsqrtf(s * (1.0f / (float)H) + EPS);
  float4 wv = ((const float4*)w)[threadIdx.x];
  __hip_bfloat16* yp = yb + (size_t)row * H + threadIdx.x * 4;
  yp[0] = __float2bfloat16(v.x * inv * wv.x);
  yp[1] = __float2bfloat16(v.y * inv * wv.y);
  yp[2] = __float2bfloat16(v.z * inv * wv.z);
  yp[3] = __float2bfloat16(v.w * inv * wv.w);
}

// -------- fused: resid = a+b; h2 = rmsnorm(resid)*w (fp32 + bf16) --------
__global__ __launch_bounds__(256) void fused_add_rms(const float* __restrict__ a,
                                                     const float* __restrict__ b,
                                                     float* __restrict__ resid,
                                                     const float* __restrict__ w,
                                                     float* __restrict__ yf,
                                                     __hip_bfloat16* __restrict__ yb) {
  int row = blockIdx.x;
  float4 av = ((const float4*)(a + (size_t)row * H))[threadIdx.x];
  float4 bv = ((const float4*)(b + (size_t)row * H))[threadIdx.x];
  float4 v = make_float4(av.x + bv.x, av.y + bv.y, av.z + bv.z, av.w + bv.w);
  ((float4*)(resid + (size_t)row * H))[threadIdx.x] = v;
  float s = v.x * v.x + v.y * v.y + v.z * v.z + v.w * v.w;
  #pragma unroll
  for (int o = 32; o; o >>= 1) s += __shfl_down(s, o, 64);
  __shared__ float red[4];
  if ((threadIdx.x & 63) == 0) red[threadIdx.x >> 6] = s;
  __syncthreads();
  s = red[0] + red[1] + red[2] + red[3];
  float inv = rsqrtf(s * (1.0f / (float)H) + EPS);
  float4 wv = ((const float4*)w)[threadIdx.x];
  float o0 = v.x * inv * wv.x, o1 = v.y * inv * wv.y, o2 = v.z * inv * wv.z, o3 = v.w * inv * wv.w;
  ((float4*)(yf + (size_t)row * H))[threadIdx.x] = make_float4(o0, o1, o2, o3);
  __hip_bfloat16* yp = yb + (size_t)row * H + threadIdx.x * 4;
  yp[0] = __float2bfloat16(o0);
  yp[1] = __float2bfloat16(o1);
  yp[2] = __float2bfloat16(o2);
  yp[3] = __float2bfloat16(o3);
}

// ------- fp32 [R][C] -> bf16 [C][R]; z batched, last z optionally from srcS -------
__global__ __launch_bounds__(256) void tcast9(const float* __restrict__ srcE,
                                              const float* __restrict__ srcS,
                                              __hip_bfloat16* __restrict__ dst, int R, int C,
                                              long long srcStride, long long dstStride,
                                              long long sBatch, long long dBatch) {
  int z = blockIdx.z;
  const float* src = (srcS && z == (int)gridDim.z - 1) ? srcS : srcE + (long long)z * sBatch;
  dst += (long long)z * dBatch;
  int c0 = blockIdx.x * 64, r0 = blockIdx.y * 32;
  __shared__ float tile[32][65];
  int tid = threadIdx.x;
  int lr = tid >> 4;
  int lc = (tid & 15) * 4;
  #pragma unroll
  for (int it = 0; it < 2; it++) {
    float4 v = *(const float4*)(src + (long long)(r0 + lr + it * 16) * srcStride + c0 + lc);
    tile[lr + it * 16][lc + 0] = v.x;
    tile[lr + it * 16][lc + 1] = v.y;
    tile[lr + it * 16][lc + 2] = v.z;
    tile[lr + it * 16][lc + 3] = v.w;
  }
  __syncthreads();
  int oc = tid >> 2;
  int rr = (tid & 3) * 8;
  short ov[8];
  #pragma unroll
  for (int i = 0; i < 8; i++) {
    __hip_bfloat16 b = __float2bfloat16(tile[rr + i][oc]);
    ov[i] = *(short*)&b;
  }
  *(bf16x8*)((short*)dst + (long long)(c0 + oc) * dstStride + r0 + rr) = *(bf16x8*)ov;
}

// ------------- bf16 MFMA GEMM, 128x64 tile, BK=64, XOR-swizzled LDS -------------
// C[M,N] = A[M,K] * Bt[N,K]^T ; last z slot (if A2) uses A2/full rows/Cout2.
__global__ __launch_bounds__(256) void gemm_bf16(const __hip_bfloat16* __restrict__ A,
                                                 const __hip_bfloat16* __restrict__ A2,
                                                 const __hip_bfloat16* __restrict__ Bt,
                                                 void* __restrict__ Cout, void* __restrict__ Cout2,
                                                 int M, int N, int K, int out_bf16,
                                                 const int* __restrict__ row_offs,
                                                 long long strideB) {
  int e = blockIdx.z;
  bool sh = (A2 != nullptr && e == (int)gridDim.z - 1);
  int rbeg = 0, rend = M;
  const __hip_bfloat16* Ap = A;
  void* Cp = Cout;
  if (sh) {
    Ap = A2; Cp = Cout2;
  } else if (row_offs) {
    rbeg = row_offs[e]; rend = row_offs[e + 1];
  }
  long long m0 = rbeg + (long long)blockIdx.y * 128;
  if (m0 >= rend) return;
  long long n0 = (long long)blockIdx.x * 64;
  const __hip_bfloat16* Bp = Bt + (long long)e * strideB;

  __shared__ unsigned short As[128 * 64];
  __shared__ unsigned short Bs[64 * 64];

  int tid = threadIdx.x;
  int lane = tid & 63, w = tid >> 6;
  int wr = (w >> 1) * 64, wc = (w & 1) * 32;
  int qd = lane >> 4, ln16 = lane & 15;
  int l7 = ln16 & 7;

  floatx4 acc[4][2];
  floatx4 zero = {0.f, 0.f, 0.f, 0.f};
  #pragma unroll
  for (int i = 0; i < 4; i++)
    #pragma unroll
    for (int j = 0; j < 2; j++) acc[i][j] = zero;

  int rowA[4], kcA[4];
  #pragma unroll
  for (int it = 0; it < 4; it++) {
    int chunk = tid + it * 256;
    rowA[it] = chunk >> 3;
    kcA[it] = ((chunk & 7) ^ (rowA[it] & 7)) * 8;
  }

  for (int k0 = 0; k0 < K; k0 += 64) {
    #pragma unroll
    for (int it = 0; it < 4; it++) {
      long long ra = m0 + rowA[it];
      if (ra >= rend) ra = rend - 1;
      gload16(Ap + ra * K + k0 + kcA[it], As + (tid + it * 256) * 8);
    }
    #pragma unroll
    for (int it = 0; it < 2; it++)
      gload16(Bp + (n0 + rowA[it]) * K + k0 + kcA[it], Bs + (tid + it * 256) * 8);
    __syncthreads();
    #pragma unroll
    for (int s = 0; s < 2; s++) {
      bf16x8 af[4], bfr[2];
      #pragma unroll
      for (int i = 0; i < 4; i++) {
        int row = wr + i * 16 + ln16;
        af[i] = *(const bf16x8*)(As + row * 64 + (((s * 4 + qd) ^ l7) * 8));
      }
      #pragma unroll
      for (int j = 0; j < 2; j++) {
        int row = wc + j * 16 + ln16;
        bfr[j] = *(const bf16x8*)(Bs + row * 64 + (((s * 4 + qd) ^ l7) * 8));
      }
      #pragma unroll
      for (int i = 0; i < 4; i++)
        #pragma unroll
        for (int j = 0; j < 2; j++)
          acc[i][j] = __builtin_amdgcn_mfma_f32_16x16x32_bf16(af[i], bfr[j], acc[i][j], 0, 0, 0);
    }
    __syncthreads();
  }

  #pragma unroll
  for (int i = 0; i < 4; i++) {
    #pragma unroll
    for (int r = 0; r < 4; r++) {
      long long gm = m0 + wr + i * 16 + qd * 4 + r;
      if (gm < rend) {
        #pragma unroll
        for (int j = 0; j < 2; j++) {
          long long gn = n0 + wc + j * 16 + ln16;
          float v = acc[i][j][r];
          if (out_bf16)
            ((__hip_bfloat16*)Cp)[gm * N + gn] = __float2bfloat16(v);
          else
            ((float*)Cp)[gm * N + gn] = v;
        }
      }
    }
  }
}

// -------- RoPE + per-head rmsnorm; Qb scaled by SCALE*log2e, Kb plain --------
__global__ __launch_bounds__(256) void rope_pack(const float* __restrict__ qkv,
                                                 const int* __restrict__ positions,
                                                 __hip_bfloat16* __restrict__ Qb,
                                                 __hip_bfloat16* __restrict__ Kb) {
  int b = blockIdx.x * 4 + (threadIdx.x >> 6);
  int t = b / (NH + NKV);
  int hh = b % (NH + NKV);
  const float* ptr = qkv + (long long)t * QKVN + hh * DH;
  int d = threadIdx.x & 63;
  float v = ptr[d];
  int fi = d & 31;
  float inv_freq = exp2f(-(float)fi * (18.93156857f / 32.0f));
  float ang = (float)positions[t] * inv_freq;
  float c = __cosf(ang), s = __sinf(ang);
  float other = __shfl_xor(v, 32, 64);
  float r = (d < 32) ? (v * c - other * s) : (v * c + other * s);
  float sq = r * r;
  #pragma unroll
  for (int off = 32; off; off >>= 1) sq += __shfl_xor(sq, off, 64);
  float o = r * rsqrtf(sq * (1.0f / (float)DH) + EPS);
  if (hh < NH)
    Qb[(size_t)t * (NH * DH) + hh * DH + d] = __float2bfloat16(o * (ATTN_SCALE * LOG2E));
  else
    Kb[(size_t)t * (NKV * DH) + (hh - NH) * DH + d] = __float2bfloat16(o);
}

// ------- MFMA flash attention: static-max softmax (no running max/rescale) -------
__global__ __launch_bounds__(256) void attn_mfma(const __hip_bfloat16* __restrict__ Qb,
                                                 const __hip_bfloat16* __restrict__ Kb,
                                                 const __hip_bfloat16* __restrict__ VtG,
                                                 __hip_bfloat16* __restrict__ ao) {
  int h = blockIdx.y;
  int kvh = h >> 2;
  int nb = gridDim.x;
  int bx = blockIdx.x;
  int qi = (bx & 1) ? (nb - 1 - (bx >> 1)) : (bx >> 1);
  int q0 = qi * 64;

  __shared__ unsigned short Ks[64 * 64];
  __shared__ unsigned short Vs[64 * 64];
  __shared__ unsigned short Ps[4 * 16 * 64];

  int tid = threadIdx.x;
  int lane = tid & 63, w = tid >> 6;
  int qd = lane >> 4, ln16 = lane & 15;
  int l7 = ln16 & 7;
  unsigned short* Pw = Ps + w * 16 * 64;

  int r0 = tid >> 3;
  int sc = ((tid & 7) ^ (r0 & 7)) * 8;

  int tq = q0 + w * 16 + ln16;
  const unsigned short* qp = (const unsigned short*)Qb + (size_t)tq * (NH * DH) + h * DH;
  bf16x8 aq[2];
  aq[0] = *(const bf16x8*)(qp + qd * 8);
  aq[1] = *(const bf16x8*)(qp + 32 + qd * 8);

  bf16x8 ones;
  #pragma unroll
  for (int i = 0; i < 8; i++) ones[i] = (short)0x3F80;  // bf16 1.0

  floatx4 O_[4], accl;
  floatx4 zero = {0.f, 0.f, 0.f, 0.f};
  #pragma unroll
  for (int j = 0; j < 4; j++) O_[j] = zero;
  accl = zero;
  int tq_base = q0 + w * 16 + qd * 4;
  int wave_min_row = q0 + w * 16;

  for (int kb = 0; kb < q0 + 64; kb += 64) {
    gload16((const unsigned short*)Kb + (size_t)(kb + r0) * (NKV * DH) + kvh * DH + sc, Ks + tid * 8);
    gload16((const unsigned short*)Kb + (size_t)(kb + r0 + 32) * (NKV * DH) + kvh * DH + sc, Ks + tid * 8 + 2048);
    gload16((const unsigned short*)VtG + (size_t)(kvh * DH + r0) * T + kb + sc, Vs + tid * 8);
    gload16((const unsigned short*)VtG + (size_t)(kvh * DH + r0 + 32) * T + kb + sc, Vs + tid * 8 + 2048);
    __syncthreads();

    floatx4 S_[4];
    #pragma unroll
    for (int j = 0; j < 4; j++) S_[j] = zero;
    #pragma unroll
    for (int s = 0; s < 2; s++) {
      bf16x8 bk[4];
      #pragma unroll
      for (int j = 0; j < 4; j++)
        bk[j] = *(const bf16x8*)(Ks + (j * 16 + ln16) * 64 + (((s * 4 + qd) ^ l7) * 8));
      #pragma unroll
      for (int j = 0; j < 4; j++)
        S_[j] = __builtin_amdgcn_mfma_f32_16x16x32_bf16(aq[s], bk[j], S_[j], 0, 0, 0);
    }

    // p = exp2(s - MBOUND); masked -> 0 (diagonal tile only)
    if (kb + 63 > wave_min_row) {
      #pragma unroll
      for (int j = 0; j < 4; j++) {
        int tk = kb + j * 16 + ln16;
        #pragma unroll
        for (int r = 0; r < 4; r++)
          S_[j][r] = (tk <= tq_base + r) ? exp2f(S_[j][r] - MBOUND) : 0.f;
      }
    } else {
      #pragma unroll
      for (int j = 0; j < 4; j++)
        #pragma unroll
        for (int r = 0; r < 4; r++) S_[j][r] = exp2f(S_[j][r] - MBOUND);
    }

    // P -> per-wave LDS (bf16, XOR swizzle)
    #pragma unroll
    for (int j = 0; j < 4; j++)
      #pragma unroll
      for (int r = 0; r < 4; r++) {
        int row = qd * 4 + r;
        int pc = (((j * 2 + (ln16 >> 3)) ^ (row & 7)) * 8) + l7;
        __hip_bfloat16 pb = __float2bfloat16(S_[j][r]);
        Pw[row * 64 + pc] = *(unsigned short*)&pb;
      }

    // O += P V ; l += P . ones
    #pragma unroll
    for (int s = 0; s < 2; s++) {
      bf16x8 ap = *(const bf16x8*)(Pw + ln16 * 64 + (((s * 4 + qd) ^ l7) * 8));
      bf16x8 bv[4];
      #pragma unroll
      for (int j = 0; j < 4; j++)
        bv[j] = *(const bf16x8*)(Vs + (j * 16 + ln16) * 64 + (((s * 4 + qd) ^ l7) * 8));
      #pragma unroll
      for (int j = 0; j < 4; j++)
        O_[j] = __builtin_amdgcn_mfma_f32_16x16x32_bf16(ap, bv[j], O_[j], 0, 0, 0);
      accl = __builtin_amdgcn_mfma_f32_16x16x32_bf16(ap, ones, accl, 0, 0, 0);
    }
    __syncthreads();
  }

  float inv[4];
  #pragma unroll
  for (int r = 0; r < 4; r++) inv[r] = 1.0f / accl[r];
  #pragma unroll
  for (int j = 0; j < 4; j++)
    #pragma unroll
    for (int r = 0; r < 4; r++)
      ao[(size_t)(tq_base + r) * (NH * DH) + h * DH + j * 16 + ln16] =
          __float2bfloat16(O_[j][r] * inv[r]);
}

// ------- fused silu-mul over expert (gA2->gP) and shared (gS2->gPs) -------
__global__ void silumul_both(const __hip_bfloat16* __restrict__ gA2,
                             const __hip_bfloat16* __restrict__ gS2,
                             __hip_bfloat16* __restrict__ gP,
                             __hip_bfloat16* __restrict__ gPs, int n4each) {
  int i = blockIdx.x * blockDim.x + threadIdx.x;
  const __hip_bfloat16* src = gA2;
  __hip_bfloat16* dst = gP;
  if (i >= n4each) {
    i -= n4each;
    src = gS2;
    dst = gPs;
  }
  int el = i * 4;
  int row = el >> 10;
  int c = el & (FF - 1);
  const __hip_bfloat16* g = src + (size_t)row * (2 * FF) + c;
  #pragma unroll
  for (int k = 0; k < 4; k++) {
    float av = __bfloat162float(g[k]);
    float bv = __bfloat162float(g[FF + k]);
    dst[el + k] = __float2bfloat16(av / (1.f + __expf(-av)) * bv);
  }
}

// ---------------- router (top-1 + sigmoid gate), fp32 ----------------
__global__ __launch_bounds__(64) void router_kernel(const float* __restrict__ h2,
                                                    const float* __restrict__ rw,
                                                    int* __restrict__ idx,
                                                    float* __restrict__ gate,
                                                    int* __restrict__ counts) {
  int t = blockIdx.x;
  int lane = threadIdx.x;
  float acc[NE] = {};
  for (int k = lane; k < H; k += 64) {
    float hv = h2[(long long)t * H + k];
    float4 r0 = *(const float4*)(rw + (long long)k * NE);
    float4 r1 = *(const float4*)(rw + (long long)k * NE + 4);
    acc[0] += hv * r0.x; acc[1] += hv * r0.y; acc[2] += hv * r0.z; acc[3] += hv * r0.w;
    acc[4] += hv * r1.x; acc[5] += hv * r1.y; acc[6] += hv * r1.z; acc[7] += hv * r1.w;
  }
  #pragma unroll
  for (int off = 32; off; off >>= 1)
    #pragma unroll
    for (int e2 = 0; e2 < NE; e2++) acc[e2] += __shfl_down(acc[e2], off, 64);
  if (lane == 0) {
    int best = 0;
    float bv = acc[0];
    #pragma unroll
    for (int e2 = 1; e2 < NE; e2++)
      if (acc[e2] > bv) { bv = acc[e2]; best = e2; }
    idx[t] = best;
    gate[t] = 1.f / (1.f + expf(-bv));
    atomicAdd(&counts[best], 1);
  }
}

__global__ void zero_counts_kernel(int* c) {
  if (threadIdx.x < 2 * NE) c[threadIdx.x] = 0;
}

__global__ void scan_kernel(const int* __restrict__ counts, int* __restrict__ offs) {
  if (threadIdx.x == 0) {
    int s = 0;
    for (int e2 = 0; e2 < NE; e2++) { offs[e2] = s; s += counts[e2]; }
    offs[NE] = s;
  }
}

__global__ void assign_kernel(const int* __restrict__ idx, const int* __restrict__ offs,
                              int* __restrict__ cnt2, int* __restrict__ perm,
                              int* __restrict__ pos) {
  int t = blockIdx.x * blockDim.x + threadIdx.x;
  if (t >= T) return;
  int e2 = idx[t];
  int p = offs[e2] + atomicAdd(&cnt2[e2], 1);
  pos[t] = p;
  perm[p] = t;
}

__global__ __launch_bounds__(256) void gather_kernel(const float* __restrict__ h2,
                                                     const float* __restrict__ gate,
                                                     const int* __restrict__ perm,
                                                     __hip_bfloat16* __restrict__ xg) {
  int p = blockIdx.x;
  int t = perm[p];
  float g = gate[t];
  float4 v = ((const float4*)(h2 + (long long)t * H))[threadIdx.x];
  __hip_bfloat16* yp = xg + (long long)p * H + threadIdx.x * 4;
  yp[0] = __float2bfloat16(v.x * g);
  yp[1] = __float2bfloat16(v.y * g);
  yp[2] = __float2bfloat16(v.z * g);
  yp[3] = __float2bfloat16(v.w * g);
}

__global__ __launch_bounds__(256) void final_add_kernel(float* __restrict__ out,
                                                        const float* __restrict__ outp,
                                                        const int* __restrict__ pos) {
  int t = blockIdx.x;
  int p = pos[t];
  const float4* src = (const float4*)(outp + (long long)p * H);
  float4* dst = (float4*)(out + (long long)t * H);
  float4 a = dst[threadIdx.x];
  float4 b = src[threadIdx.x];
  a.x += b.x; a.y += b.y; a.z += b.z; a.w += b.w;
  dst[threadIdx.x] = a;
}

// ---------------- launcher ----------------
extern "C" void kernel_launch(void* const* d_in, const int* in_sizes, int n_in,
                              void* d_out, int out_size, void* d_ws, size_t ws_size,
                              hipStream_t stream) {
  const int* positions = (const int*)d_in[0];
  const float* hidden = (const float*)d_in[1];
  const float* ln1_w = (const float*)d_in[2];
  const float* ln2_w = (const float*)d_in[3];
  const float* wqkv = (const float*)d_in[4];
  const float* wo = (const float*)d_in[5];
  const float* router_w = (const float*)d_in[6];
  const float* w_gate = (const float*)d_in[7];
  const float* w_up = (const float*)d_in[8];
  const float* w_down = (const float*)d_in[9];
  const float* sh_gate = (const float*)d_in[10];
  const float* sh_up = (const float*)d_in[11];
  const float* sh_down = (const float*)d_in[12];

  float* out = (float*)d_out;
  float* resid = out + (size_t)T * H;

  char* p = (char*)d_ws;
  auto alloc = [&](size_t bytes) { char* r = p; p += (bytes + 255) & ~(size_t)255; return r; };

  float* qkv = (float*)alloc((size_t)T * QKVN * 4);
  float* h2 = (float*)alloc((size_t)T * H * 4);
  float* gb1 = (float*)alloc((size_t)T * H * 4);    // wo out; later aliased as gS2
  float* outp = (float*)alloc((size_t)T * H * 4);
  __hip_bfloat16* h1b = (__hip_bfloat16*)alloc((size_t)T * H * 2);  // later aliased as gPs
  __hip_bfloat16* aob = (__hip_bfloat16*)alloc((size_t)T * H * 2);
  __hip_bfloat16* h2b = (__hip_bfloat16*)alloc((size_t)T * H * 2);
  __hip_bfloat16* xgb = (__hip_bfloat16*)alloc((size_t)T * H * 2);
  __hip_bfloat16* gA2 = (__hip_bfloat16*)alloc((size_t)T * 2 * FF * 2);
  __hip_bfloat16* gP = (__hip_bfloat16*)alloc((size_t)T * FF * 2);
  __hip_bfloat16* Qb = (__hip_bfloat16*)alloc((size_t)T * NH * DH * 2);
  __hip_bfloat16* Kb = (__hip_bfloat16*)alloc((size_t)T * NKV * DH * 2);
  __hip_bfloat16* VtG = (__hip_bfloat16*)alloc((size_t)NKV * DH * T * 2);
  __hip_bfloat16* wqkvT = (__hip_bfloat16*)alloc((size_t)H * QKVN * 2);
  __hip_bfloat16* woT = (__hip_bfloat16*)alloc((size_t)H * H * 2);
  __hip_bfloat16* wguT = (__hip_bfloat16*)alloc((size_t)9 * 2 * FF * H * 2);  // slot 8 = shared
  __hip_bfloat16* wdT = (__hip_bfloat16*)alloc((size_t)9 * H * FF * 2);       // slot 8 = shared
  int* counts = (int*)alloc(2 * NE * 4);
  int* cnt2 = counts + NE;
  int* offs = (int*)alloc((NE + 1) * 4);
  int* idx = (int*)alloc(T * 4);
  int* perm = (int*)alloc(T * 4);
  int* pos = (int*)alloc(T * 4);
  float* gate = (float*)alloc(T * 4);

  // dead-buffer aliases (gb1 dead after fused_add_rms; h1b dead after qkv GEMM)
  __hip_bfloat16* gS2 = (__hip_bfloat16*)gb1;   // T*2FF bf16 = T*H fp32 bytes
  __hip_bfloat16* gPs = h1b;                    // T*FF bf16 <= T*H bf16

  // weight transpose+cast (5 launches)
  tcast9<<<dim3(QKVN / 64, H / 32, 1), 256, 0, stream>>>(wqkv, nullptr, wqkvT, H, QKVN, QKVN, H, 0, 0);
  tcast9<<<dim3(H / 64, H / 32, 1), 256, 0, stream>>>(wo, nullptr, woT, H, H, H, H, 0, 0);
  tcast9<<<dim3(FF / 64, H / 32, 9), 256, 0, stream>>>(w_gate, sh_gate, wguT, H, FF, FF, H,
                                                       (long long)H * FF, (long long)2 * H * FF);
  tcast9<<<dim3(FF / 64, H / 32, 9), 256, 0, stream>>>(w_up, sh_up, wguT + (size_t)FF * H, H, FF, FF, H,
                                                       (long long)H * FF, (long long)2 * H * FF);
  tcast9<<<dim3(H / 64, FF / 32, 9), 256, 0, stream>>>(w_down, sh_down, wdT, FF, H, H, FF,
                                                       (long long)FF * H, (long long)H * FF);

  // 1. h1b = bf16(rmsnorm(hidden) * ln1_w)
  rmsnorm1024<<<T, 256, 0, stream>>>(hidden, ln1_w, h1b);
  // 2. qkv = h1 @ wqkv (fp32)
  gemm_bf16<<<dim3(QKVN / 64, T / 128, 1), 256, 0, stream>>>(h1b, nullptr, wqkvT, qkv, nullptr,
                                                             T, QKVN, H, 0, nullptr, 0);
  // 3. RoPE + q/k rmsnorm -> Qb (pre-scaled), Kb
  rope_pack<<<T * (NH + NKV) / 4, 256, 0, stream>>>(qkv, positions, Qb, Kb);
  // 4a. V^T bf16 [NKV*DH][T]
  tcast9<<<dim3(NKV * DH / 64, T / 32, 1), 256, 0, stream>>>(qkv + (NH + NKV) * DH, nullptr, VtG,
                                                             T, NKV * DH, QKVN, T, 0, 0);
  // 4b. attention
  attn_mfma<<<dim3(T / 64, NH), 256, 0, stream>>>(Qb, Kb, VtG, aob);
  // 5. gb1 = ao @ wo (fp32)
  gemm_bf16<<<dim3(H / 64, T / 128, 1), 256, 0, stream>>>(aob, nullptr, woT, gb1, nullptr,
                                                          T, H, H, 0, nullptr, 0);
  // 6+7. resid = gb1 + hidden; h2 = rmsnorm(resid)*ln2_w
  fused_add_rms<<<T, 256, 0, stream>>>(gb1, hidden, resid, ln2_w, h2, h2b);
  // 8-11. routing
  zero_counts_kernel<<<1, 64, 0, stream>>>(counts);
  router_kernel<<<T, 64, 0, stream>>>(h2, router_w, idx, gate, counts);
  scan_kernel<<<1, 64, 0, stream>>>(counts, offs);
  assign_kernel<<<T / 256, 256, 0, stream>>>(idx, offs, cnt2, perm, pos);
  // 12. gather
  gather_kernel<<<T, 256, 0, stream>>>(h2, gate, perm, xgb);
  // 13. gate+up: experts (z=0..7 grouped) + shared (z=8, h2b -> gS2)
  gemm_bf16<<<dim3(2 * FF / 64, T / 128, 9), 256, 0, stream>>>(xgb, h2b, wguT, gA2, gS2,
                                                               T, 2 * FF, H, 1, offs,
                                                               (long long)2 * H * FF);
  // 14. silu-mul both
  silumul_both<<<(2 * T * FF / 4) / 256, 256, 0, stream>>>(gA2, gS2, gP, gPs, T * FF / 4);
  // 15. down: experts -> outp (fp32), shared -> out (fp32)
  gemm_bf16<<<dim3(H / 64, T / 128, 9), 256, 0, stream>>>(gP, gPs, wdT, outp, out,
                                                          T, H, FF, 0, offs, (long long)FF * H);
  // 16. out += routed
  final_add_kernel<<<T, 256, 0, stream>>>(out, outp, pos);
}